// Round 4
// baseline (696.956 us; speedup 1.0000x reference)
//
#include <hip/hip_runtime.h>
#include <stdint.h>

typedef unsigned short u16;
typedef __attribute__((ext_vector_type(8))) short bf16x8;
typedef __attribute__((ext_vector_type(4))) float f32x4;
typedef __attribute__((ext_vector_type(4))) unsigned short u16x4;

#define AS1 __attribute__((address_space(1)))
#define AS3 __attribute__((address_space(3)))

static __device__ __forceinline__ u16 f2bf(float f) {
  union { float f; uint32_t u; } c; c.f = f;
  return (u16)((c.u + 0x7FFFu + ((c.u >> 16) & 1u)) >> 16);
}

// ---- x (f32) -> bf16 ----
__global__ __launch_bounds__(256) void k_convert_x(const float* __restrict__ x,
                                                   u16* __restrict__ abf) {
  int i = blockIdx.x * 256 + threadIdx.x;
  float4 v = reinterpret_cast<const float4*>(x)[i];
  u16x4 o = { f2bf(v.x), f2bf(v.y), f2bf(v.z), f2bf(v.w) };
  reinterpret_cast<u16x4*>(abf)[i] = o;
}

// ---- w[t][d][e] f32 -> bt[t][e][d] bf16 ----
__global__ __launch_bounds__(256) void k_transpose_w(const float* __restrict__ w,
                                                     u16* __restrict__ bt) {
  __shared__ u16 tile[64][65];
  const int t = blockIdx.z;
  const int e0 = blockIdx.x * 64, d0 = blockIdx.y * 64;
  const int tx = threadIdx.x & 63, ty = threadIdx.x >> 6;
  const float* wp = w + ((size_t)t << 20);
  u16* bp = bt + ((size_t)t << 20);
  for (int rr = 0; rr < 16; ++rr) {
    int r = rr * 4 + ty;
    tile[r][tx] = f2bf(wp[(size_t)(d0 + r) * 1024 + (e0 + tx)]);
  }
  __syncthreads();
  for (int rr = 0; rr < 16; ++rr) {
    int r = rr * 4 + ty;
    bp[(size_t)(e0 + r) * 1024 + (d0 + tx)] = tile[tx][r];
  }
}

// ---- W2f[t][d][k] += w[t][d,:]·ww[t][:,k] over e-range; MFMA, e-split x4 ----
__global__ __launch_bounds__(256) void k_w2(const float* __restrict__ w,
                                            const float* __restrict__ ww,
                                            float* __restrict__ w2f) {
  __shared__ float wwT[16][264];
  const int tid = threadIdx.x, lane = tid & 63, wv = tid >> 6;
  const int t = blockIdx.y;
  const int d0 = blockIdx.x * 128 + wv * 32;
  const int ez = blockIdx.z * 256;
  const int fr = lane & 15, koff = (lane >> 4) * 8;
  const float* wp = w + ((size_t)t << 20);
  const float* wwp = ww + (t << 14);
  for (int it = 0; it < 16; ++it) {
    int idx = it * 256 + tid;   // 4096 = 256 e x 16 k
    wwT[idx & 15][idx >> 4] = wwp[(size_t)(ez + (idx >> 4)) * 16 + (idx & 15)];
  }
  __syncthreads();
  f32x4 acc[2] = {};
  for (int kk = 0; kk < 256; kk += 32) {
    const int eL = kk + koff;
    float4 b0 = *(const float4*)&wwT[fr][eL];
    float4 b1 = *(const float4*)&wwT[fr][eL + 4];
    bf16x8 b;
    ((u16*)&b)[0] = f2bf(b0.x); ((u16*)&b)[1] = f2bf(b0.y);
    ((u16*)&b)[2] = f2bf(b0.z); ((u16*)&b)[3] = f2bf(b0.w);
    ((u16*)&b)[4] = f2bf(b1.x); ((u16*)&b)[5] = f2bf(b1.y);
    ((u16*)&b)[6] = f2bf(b1.z); ((u16*)&b)[7] = f2bf(b1.w);
#pragma unroll
    for (int m = 0; m < 2; ++m) {
      const float* ap = wp + (size_t)(d0 + m * 16 + fr) * 1024 + ez + eL;
      float4 a0 = *(const float4*)ap;
      float4 a1 = *(const float4*)(ap + 4);
      bf16x8 a;
      ((u16*)&a)[0] = f2bf(a0.x); ((u16*)&a)[1] = f2bf(a0.y);
      ((u16*)&a)[2] = f2bf(a0.z); ((u16*)&a)[3] = f2bf(a0.w);
      ((u16*)&a)[4] = f2bf(a1.x); ((u16*)&a)[5] = f2bf(a1.y);
      ((u16*)&a)[6] = f2bf(a1.z); ((u16*)&a)[7] = f2bf(a1.w);
      acc[m] = __builtin_amdgcn_mfma_f32_16x16x32_bf16(a, b, acc[m], 0, 0, 0);
    }
  }
#pragma unroll
  for (int m = 0; m < 2; ++m)
#pragma unroll
    for (int i = 0; i < 4; ++i) {
      int d = d0 + m * 16 + ((lane >> 4) << 2) + i;
      unsafeAtomicAdd(&w2f[(((size_t)t << 10) + d) * 16 + fr], acc[m][i]);
    }
}

// ---- BT2[144][1024] bf16 = [wread | W2]^T ----
__global__ __launch_bounds__(256) void k_bt2(const float* __restrict__ wread,
                                             const float* __restrict__ w2f,
                                             u16* __restrict__ bt2) {
  int i = blockIdx.x * 256 + threadIdx.x;   // < 147456
  int r = i >> 10, d = i & 1023;
  float v;
  if (r < 16) v = wread[d * 16 + r];
  else { int t = (r - 16) >> 4, k = (r - 16) & 15; v = w2f[(((size_t)t << 10) + d) * 16 + k]; }
  bt2[i] = f2bf(v);
}

// ---- P[n][144] += Abf @ BT2^T over k-range; k-split x4 ----
__global__ __launch_bounds__(256) void k_p(const u16* __restrict__ abf,
                                           const u16* __restrict__ bt2,
                                           float* __restrict__ P) {
  const int tid = threadIdx.x, lane = tid & 63, wv = tid >> 6;
  const int row0 = blockIdx.x * 64 + wv * 16;
  const int k0 = blockIdx.y * 256;
  const int fr = lane & 15, koff = (lane >> 4) * 8;
  f32x4 acc[9] = {};
  for (int kk = 0; kk < 256; kk += 32) {
    bf16x8 a = *(const bf16x8*)&abf[(size_t)(row0 + fr) * 1024 + k0 + kk + koff];
#pragma unroll
    for (int n = 0; n < 9; ++n) {
      bf16x8 b = *(const bf16x8*)&bt2[(size_t)(n * 16 + fr) * 1024 + k0 + kk + koff];
      acc[n] = __builtin_amdgcn_mfma_f32_16x16x32_bf16(a, b, acc[n], 0, 0, 0);
    }
  }
  const int rbase = row0 + ((lane >> 4) << 2);
#pragma unroll
  for (int n = 0; n < 9; ++n)
#pragma unroll
    for (int i = 0; i < 4; ++i)
      unsafeAtomicAdd(&P[(size_t)(rbase + i) * 144 + n * 16 + fr], acc[n][i]);
}

// ---- logits -> softmax -> att[n][8] ----
__global__ __launch_bounds__(256) void k_soft(const float* __restrict__ P,
                                              float* __restrict__ att) {
  __shared__ float lg[32][8];
  const int rl = threadIdx.x >> 3, tt = threadIdx.x & 7;
  const int r = blockIdx.x * 32 + rl;
  const float* p = P + (size_t)r * 144;
  float4 x0 = *(const float4*)(p),     x1 = *(const float4*)(p + 4),
         x2 = *(const float4*)(p + 8), x3 = *(const float4*)(p + 12);
  const float* q = p + 16 + tt * 16;
  float4 y0 = *(const float4*)(q),     y1 = *(const float4*)(q + 4),
         y2 = *(const float4*)(q + 8), y3 = *(const float4*)(q + 12);
  float acc = x0.x*y0.x + x0.y*y0.y + x0.z*y0.z + x0.w*y0.w
            + x1.x*y1.x + x1.y*y1.y + x1.z*y1.z + x1.w*y1.w
            + x2.x*y2.x + x2.y*y2.y + x2.z*y2.z + x2.w*y2.w
            + x3.x*y3.x + x3.y*y3.y + x3.z*y3.z + x3.w*y3.w;
  lg[rl][tt] = acc;
  __syncthreads();
  float m = lg[rl][0];
#pragma unroll
  for (int j = 1; j < 8; ++j) m = fmaxf(m, lg[rl][j]);
  float s = 0.f;
#pragma unroll
  for (int j = 0; j < 8; ++j) s += __expf(lg[rl][j] - m);
  att[(size_t)r * 8 + tt] = __expf(lg[rl][tt] - m) / s;
}

// ======== main GEMM: 256x256 tile, BK=32, 4-phase/K-tile, 2 blocks/CU ========
// 64 K-tiles (2 t's x 32), double-buffered 32KB halves, counted vmcnt(5)/(4).
// LDS: buf0 [0,32K) = A[256][32]|B[256][32]; buf1 [32K,64K); att @64K; dummy @67584.
// Swizzle: 16B granule pos = g ^ ((row>>1)&3); balanced b128 (8 lanes/4-bank grp).
#define BAR()   asm volatile("s_barrier" ::: "memory")
#define LGKM0() asm volatile("s_waitcnt lgkmcnt(0)" ::: "memory")
#define VM5()   asm volatile("s_waitcnt vmcnt(5)" ::: "memory")
#define VM4()   asm volatile("s_waitcnt vmcnt(4)" ::: "memory")
#define VM3()   asm volatile("s_waitcnt vmcnt(3)" ::: "memory")

__global__ __launch_bounds__(512, 4) void k_gemm256(const u16* __restrict__ abf,
                                                    const u16* __restrict__ bt,
                                                    const float* __restrict__ att,
                                                    float* __restrict__ out) {
  __shared__ char lds[75776];
  float* lAtt = (float*)(lds + 65536);   // [256][2]

  const int tid  = threadIdx.x;
  const int lane = tid & 63;
  const int wv   = tid >> 6;          // 0..7
  const int wr = wv >> 2, wc = wv & 3;

  int id = (blockIdx.z * gridDim.y + blockIdx.y) * gridDim.x + blockIdx.x; // 0..255
  int sw = (id & 7) * 32 + (id >> 3);         // XCD chunk swizzle (bijective)
  const int bx = sw & 3, by = (sw >> 2) & 15, bz = sw >> 6;
  const int bm = by * 256, bn = bx * 256, t0 = bz * 2;

  { int r = tid >> 1, c = tid & 1;
    lAtt[r * 2 + c] = att[(size_t)(bm + r) * 8 + t0 + c]; }

  const int l15 = lane & 15, lq = lane >> 4;
  const int apos  = ((lq ^ ((l15 >> 1) & 3)) * 16);     // read-side swizzled granule
  const int srow  = lane >> 2;                          // stage row within 16-row chunk
  const int sgran = (((lane & 3) ^ ((lane >> 3) & 3)) * 16); // stage src granule
  const int aRd = (wr * 128 + l15) * 64 + apos;
  const int bRd = 16384 + (wc * 64 + l15) * 64 + apos;
  const char* Abase = (const char*)abf;
  const char* Bbase = (const char*)bt;

#define STAGE_A(u, js_) do {                                                \
    int js = (js_); int dm = js > 63; if (dm) js = 63;                      \
    const char* s_ = Abase + (size_t)(bm + (u) * 128 + wv * 16 + srow) * 2048 \
                   + (js & 31) * 64 + sgran;                                \
    char* d_ = dm ? (lds + 67584 + wv * 1024)                               \
                  : (lds + (js & 1) * 32768 + (u) * 8192 + wv * 1024);      \
    __builtin_amdgcn_global_load_lds((const AS1 void*)s_, (AS3 void*)d_, 16, 0, 0); \
  } while (0)
#define STAGE_B(u, js_) do {                                                \
    int js = (js_); int dm = js > 63; if (dm) js = 63;                      \
    const char* s_ = Bbase + ((size_t)(t0 + (js >> 5)) << 21)               \
                   + (size_t)(bn + (u) * 128 + wv * 16 + srow) * 2048       \
                   + (js & 31) * 64 + sgran;                                \
    char* d_ = dm ? (lds + 67584 + wv * 1024)                               \
                  : (lds + (js & 1) * 32768 + 16384 + (u) * 8192 + wv * 1024); \
    __builtin_amdgcn_global_load_lds((const AS1 void*)s_, (AS3 void*)d_, 16, 0, 0); \
  } while (0)
#define LDA(bufc, h, ar) do {                                               \
    const char* p_ = lds + (bufc) + ((h) * 64) * 64 + aRd;                  \
    _Pragma("unroll") for (int mm = 0; mm < 4; ++mm)                        \
      ar[mm] = *(const bf16x8*)(p_ + mm * 1024);                            \
  } while (0)
#define LDB(bufc, g, br) do {                                               \
    const char* p_ = lds + (bufc) + ((g) * 32) * 64 + bRd;                  \
    _Pragma("unroll") for (int nn = 0; nn < 2; ++nn)                        \
      br[nn] = *(const bf16x8*)(p_ + nn * 1024);                            \
  } while (0)
#define MFQ(h, g, ar, br) do {                                              \
    __builtin_amdgcn_s_setprio(1);                                          \
    _Pragma("unroll") for (int mm = 0; mm < 4; ++mm)                        \
    _Pragma("unroll") for (int nn = 0; nn < 2; ++nn)                        \
      acc[(h)*4+mm][(g)*2+nn] = __builtin_amdgcn_mfma_f32_16x16x32_bf16(    \
          ar[mm], br[nn], acc[(h)*4+mm][(g)*2+nn], 0, 0, 0);                \
    __builtin_amdgcn_s_setprio(0);                                          \
  } while (0)

  f32x4 acc[8][4] = {};
  bf16x8 a0[4], a1[4], b0[2], b1[2];

  // prologue: tile0 complete, tile1 sans A1; drain tile0 (leave 3 newest)
  STAGE_A(0, 0); STAGE_B(0, 0); STAGE_B(1, 0); STAGE_A(1, 0);
  STAGE_B(0, 1); STAGE_B(1, 1); STAGE_A(0, 1);
  VM3(); BAR();

  for (int j = 0; j < 64; ++j) {
    const int bufc = (j & 1) * 32768;
    if (j == 32) {   // t-boundary: acc *= att_t0/att_t1 (ratio fold)
#pragma unroll
      for (int im = 0; im < 8; ++im)
#pragma unroll
        for (int ii = 0; ii < 4; ++ii) {
          const int rl = wr * 128 + im * 16 + lq * 4 + ii;
          const float sc = lAtt[rl * 2] / lAtt[rl * 2 + 1];
#pragma unroll
          for (int in = 0; in < 4; ++in) acc[im][in][ii] *= sc;
        }
    }
    // ph0: consume A0,B0; stage A1(j+1)
    LDA(bufc, 0, a0); LDB(bufc, 0, b0); STAGE_A(1, j + 1);
    BAR(); LGKM0(); MFQ(0, 0, a0, b0); BAR();
    // ph1: consume B1 (A0 regs); stage B0(j+2); guarantee A1(j) landed
    LDB(bufc, 1, b1); STAGE_B(0, j + 2);
    BAR(); LGKM0(); MFQ(0, 1, a0, b1); VM5(); BAR();
    // ph2: consume A1 (B1 regs); stage B1(j+2)
    LDA(bufc, 1, a1); STAGE_B(1, j + 2);
    BAR(); LGKM0(); MFQ(1, 1, a1, b1); BAR();
    // ph3: A1+B0 regs; stage A0(j+2); guarantee tile j+1 (A0,B0,B1) landed
    STAGE_A(0, j + 2);
    BAR(); MFQ(1, 0, a1, b0); VM4(); BAR();
  }

  // epilogue: scale by att_t1, atomic-accumulate across z-splits
#pragma unroll
  for (int im = 0; im < 8; ++im)
#pragma unroll
    for (int ii = 0; ii < 4; ++ii) {
      const int rl = wr * 128 + im * 16 + lq * 4 + ii;
      const float sc = lAtt[rl * 2 + 1];
      const int row = bm + rl;
#pragma unroll
      for (int in = 0; in < 4; ++in) {
        const int col = bn + wc * 64 + in * 16 + l15;
        unsafeAtomicAdd(&out[(size_t)row * 1024 + col], acc[im][in][ii] * sc);
      }
    }
#undef STAGE_A
#undef STAGE_B
#undef LDA
#undef LDB
#undef MFQ
}

extern "C" void kernel_launch(void* const* d_in, const int* in_sizes, int n_in,
                              void* d_out, int out_size, void* d_ws, size_t ws_size,
                              hipStream_t stream) {
  (void)in_sizes; (void)n_in; (void)ws_size;
  const float* x      = (const float*)d_in[0];   // (512,8,1024)
  const float* w      = (const float*)d_in[1];   // (8,1024,1024)
  const float* wread  = (const float*)d_in[2];   // (1,1024,16)
  const float* wwrite = (const float*)d_in[3];   // (8,1024,16)
  float* out = (float*)d_out;                    // (512,8,1024) f32

  char* ws = (char*)d_ws;
  u16*   Abf = (u16*)ws;                                    // 8 MiB
  u16*   BT  = (u16*)(ws + (8ull << 20));                   // 16 MiB
  u16*   BT2 = (u16*)(ws + (24ull << 20));                  // 288 KiB
  float* P   = (float*)(ws + (25ull << 20));                // 2.25 MiB
  float* att = (float*)(ws + (28ull << 20));                // 128 KiB
  float* W2f = (float*)(ws + (28ull << 20) + (128ull << 10)); // 512 KiB

  k_convert_x<<<4096, 256, 0, stream>>>(x, Abf);
  k_transpose_w<<<dim3(16, 16, 8), 256, 0, stream>>>(w, BT);
  hipMemsetAsync(W2f, 0, 8 * 1024 * 16 * sizeof(float), stream);
  hipMemsetAsync(P, 0, 4096 * 144 * sizeof(float), stream);
  k_w2<<<dim3(8, 8, 4), 256, 0, stream>>>(w, wwrite, W2f);
  k_bt2<<<576, 256, 0, stream>>>(wread, W2f, BT2);
  k_p<<<dim3(64, 4), 256, 0, stream>>>(Abf, BT2, P);
  k_soft<<<128, 256, 0, stream>>>(P, att);
  hipMemsetAsync(d_out, 0, (size_t)out_size * sizeof(float), stream);
  k_gemm256<<<dim3(4, 16, 4), 512, 0, stream>>>(Abf, BT, att, out);
}

// Round 5
// 165.686 us; speedup vs baseline: 4.2065x; 4.2065x over previous
//
#include <hip/hip_runtime.h>
#include <stdint.h>

typedef unsigned short u16;
typedef __attribute__((ext_vector_type(8))) short bf16x8;
typedef __attribute__((ext_vector_type(4))) float f32x4;
typedef __attribute__((ext_vector_type(4))) unsigned short u16x4;

#define AS1 __attribute__((address_space(1)))
#define AS3 __attribute__((address_space(3)))

static __device__ __forceinline__ u16 f2bf(float f) {
  union { float f; uint32_t u; } c; c.f = f;
  return (u16)((c.u + 0x7FFFu + ((c.u >> 16) & 1u)) >> 16);
}

// ---- x (f32) -> bf16 ----
__global__ __launch_bounds__(256) void k_convert_x(const float* __restrict__ x,
                                                   u16* __restrict__ abf) {
  int i = blockIdx.x * 256 + threadIdx.x;
  float4 v = reinterpret_cast<const float4*>(x)[i];
  u16x4 o = { f2bf(v.x), f2bf(v.y), f2bf(v.z), f2bf(v.w) };
  reinterpret_cast<u16x4*>(abf)[i] = o;
}

// ---- w[t][d][e] f32 -> bt[t][e][d] bf16 ----
__global__ __launch_bounds__(256) void k_transpose_w(const float* __restrict__ w,
                                                     u16* __restrict__ bt) {
  __shared__ u16 tile[64][65];
  const int t = blockIdx.z;
  const int e0 = blockIdx.x * 64, d0 = blockIdx.y * 64;
  const int tx = threadIdx.x & 63, ty = threadIdx.x >> 6;
  const float* wp = w + ((size_t)t << 20);
  u16* bp = bt + ((size_t)t << 20);
  for (int rr = 0; rr < 16; ++rr) {
    int r = rr * 4 + ty;
    tile[r][tx] = f2bf(wp[(size_t)(d0 + r) * 1024 + (e0 + tx)]);
  }
  __syncthreads();
  for (int rr = 0; rr < 16; ++rr) {
    int r = rr * 4 + ty;
    bp[(size_t)(e0 + r) * 1024 + (d0 + tx)] = tile[tx][r];
  }
}

// ---- W2f[t][d][k] += w[t][d,:]·ww[t][:,k] over e-range; MFMA, e-split x4 ----
__global__ __launch_bounds__(256) void k_w2(const float* __restrict__ w,
                                            const float* __restrict__ ww,
                                            float* __restrict__ w2f) {
  __shared__ float wwT[16][264];
  const int tid = threadIdx.x, lane = tid & 63, wv = tid >> 6;
  const int t = blockIdx.y;
  const int d0 = blockIdx.x * 128 + wv * 32;
  const int ez = blockIdx.z * 256;
  const int fr = lane & 15, koff = (lane >> 4) * 8;
  const float* wp = w + ((size_t)t << 20);
  const float* wwp = ww + (t << 14);
  for (int it = 0; it < 16; ++it) {
    int idx = it * 256 + tid;   // 4096 = 256 e x 16 k
    wwT[idx & 15][idx >> 4] = wwp[(size_t)(ez + (idx >> 4)) * 16 + (idx & 15)];
  }
  __syncthreads();
  f32x4 acc[2] = {};
  for (int kk = 0; kk < 256; kk += 32) {
    const int eL = kk + koff;
    float4 b0 = *(const float4*)&wwT[fr][eL];
    float4 b1 = *(const float4*)&wwT[fr][eL + 4];
    bf16x8 b;
    ((u16*)&b)[0] = f2bf(b0.x); ((u16*)&b)[1] = f2bf(b0.y);
    ((u16*)&b)[2] = f2bf(b0.z); ((u16*)&b)[3] = f2bf(b0.w);
    ((u16*)&b)[4] = f2bf(b1.x); ((u16*)&b)[5] = f2bf(b1.y);
    ((u16*)&b)[6] = f2bf(b1.z); ((u16*)&b)[7] = f2bf(b1.w);
#pragma unroll
    for (int m = 0; m < 2; ++m) {
      const float* ap = wp + (size_t)(d0 + m * 16 + fr) * 1024 + ez + eL;
      float4 a0 = *(const float4*)ap;
      float4 a1 = *(const float4*)(ap + 4);
      bf16x8 a;
      ((u16*)&a)[0] = f2bf(a0.x); ((u16*)&a)[1] = f2bf(a0.y);
      ((u16*)&a)[2] = f2bf(a0.z); ((u16*)&a)[3] = f2bf(a0.w);
      ((u16*)&a)[4] = f2bf(a1.x); ((u16*)&a)[5] = f2bf(a1.y);
      ((u16*)&a)[6] = f2bf(a1.z); ((u16*)&a)[7] = f2bf(a1.w);
      acc[m] = __builtin_amdgcn_mfma_f32_16x16x32_bf16(a, b, acc[m], 0, 0, 0);
    }
  }
#pragma unroll
  for (int m = 0; m < 2; ++m)
#pragma unroll
    for (int i = 0; i < 4; ++i) {
      int d = d0 + m * 16 + ((lane >> 4) << 2) + i;
      unsafeAtomicAdd(&w2f[(((size_t)t << 10) + d) * 16 + fr], acc[m][i]);
    }
}

// ---- BT2[144][1024] bf16 = [wread | W2]^T ----
__global__ __launch_bounds__(256) void k_bt2(const float* __restrict__ wread,
                                             const float* __restrict__ w2f,
                                             u16* __restrict__ bt2) {
  int i = blockIdx.x * 256 + threadIdx.x;   // < 147456
  int r = i >> 10, d = i & 1023;
  float v;
  if (r < 16) v = wread[d * 16 + r];
  else { int t = (r - 16) >> 4, k = (r - 16) & 15; v = w2f[(((size_t)t << 10) + d) * 16 + k]; }
  bt2[i] = f2bf(v);
}

// ---- P[n][144] += Abf @ BT2^T over k-range; k-split x4 ----
__global__ __launch_bounds__(256) void k_p(const u16* __restrict__ abf,
                                           const u16* __restrict__ bt2,
                                           float* __restrict__ P) {
  const int tid = threadIdx.x, lane = tid & 63, wv = tid >> 6;
  const int row0 = blockIdx.x * 64 + wv * 16;
  const int k0 = blockIdx.y * 256;
  const int fr = lane & 15, koff = (lane >> 4) * 8;
  f32x4 acc[9] = {};
  for (int kk = 0; kk < 256; kk += 32) {
    bf16x8 a = *(const bf16x8*)&abf[(size_t)(row0 + fr) * 1024 + k0 + kk + koff];
#pragma unroll
    for (int n = 0; n < 9; ++n) {
      bf16x8 b = *(const bf16x8*)&bt2[(size_t)(n * 16 + fr) * 1024 + k0 + kk + koff];
      acc[n] = __builtin_amdgcn_mfma_f32_16x16x32_bf16(a, b, acc[n], 0, 0, 0);
    }
  }
  const int rbase = row0 + ((lane >> 4) << 2);
#pragma unroll
  for (int n = 0; n < 9; ++n)
#pragma unroll
    for (int i = 0; i < 4; ++i)
      unsafeAtomicAdd(&P[(size_t)(rbase + i) * 144 + n * 16 + fr], acc[n][i]);
}

// ---- logits -> softmax -> att[n][8] ----
__global__ __launch_bounds__(256) void k_soft(const float* __restrict__ P,
                                              float* __restrict__ att) {
  __shared__ float lg[32][8];
  const int rl = threadIdx.x >> 3, tt = threadIdx.x & 7;
  const int r = blockIdx.x * 32 + rl;
  const float* p = P + (size_t)r * 144;
  float4 x0 = *(const float4*)(p),     x1 = *(const float4*)(p + 4),
         x2 = *(const float4*)(p + 8), x3 = *(const float4*)(p + 12);
  const float* q = p + 16 + tt * 16;
  float4 y0 = *(const float4*)(q),     y1 = *(const float4*)(q + 4),
         y2 = *(const float4*)(q + 8), y3 = *(const float4*)(q + 12);
  float acc = x0.x*y0.x + x0.y*y0.y + x0.z*y0.z + x0.w*y0.w
            + x1.x*y1.x + x1.y*y1.y + x1.z*y1.z + x1.w*y1.w
            + x2.x*y2.x + x2.y*y2.y + x2.z*y2.z + x2.w*y2.w
            + x3.x*y3.x + x3.y*y3.y + x3.z*y3.z + x3.w*y3.w;
  lg[rl][tt] = acc;
  __syncthreads();
  float m = lg[rl][0];
#pragma unroll
  for (int j = 1; j < 8; ++j) m = fmaxf(m, lg[rl][j]);
  float s = 0.f;
#pragma unroll
  for (int j = 0; j < 8; ++j) s += __expf(lg[rl][j] - m);
  att[(size_t)r * 8 + tt] = __expf(lg[rl][tt] - m) / s;
}

// ======== main GEMM: 256x256 tile, BK=64, 2 phases/K-tile (32 MFMA each) ========
// Round-3 indexing/swizzle verbatim; restructured schedule: per K-tile j,
//   phA: read A0,B0,B1; stage A1(j+1)->buf^1; 32 MFMA (A0xB0, A0xB1)
//   phB: read A1; stage A0,B0,B1(j+2)->buf;   32 MFMA (A1xB1, A1xB0)
// Uniform vmcnt(8) at each phase end (each staged unit lands 1 iter after
// issue, >=1 barrier before its ds_read). Tail: clamp stage source to tile 31.
#define BAR()   asm volatile("s_barrier" ::: "memory")
#define LGKM0() asm volatile("s_waitcnt lgkmcnt(0)" ::: "memory")
#define VM8()   asm volatile("s_waitcnt vmcnt(8)" ::: "memory")
#define VM6()   asm volatile("s_waitcnt vmcnt(6)" ::: "memory")

__global__ __launch_bounds__(512, 2) void k_gemm256(const u16* __restrict__ abf,
                                                    const u16* __restrict__ bt,
                                                    const float* __restrict__ att,
                                                    float* __restrict__ out) {
  __shared__ char lds[133120];
  float* lAtt = (float*)(lds + 131072);   // [256][2]

  const int tid = threadIdx.x;
  const int lane = tid & 63;
  const int wv = tid >> 6;            // 0..7
  const int wr = wv >> 2, wc = wv & 3;

  int id = (blockIdx.z * gridDim.y + blockIdx.y) * gridDim.x + blockIdx.x; // 0..255
  int sw = (id & 7) * 32 + (id >> 3);         // XCD chunk swizzle (bijective)
  const int bx = sw & 3, by = (sw >> 2) & 15, bz = sw >> 6;
  const int bm = by * 256, bn = bx * 256, t0 = bz * 2;

  { int r = tid >> 1, c = tid & 1;
    lAtt[r * 2 + c] = att[(size_t)(bm + r) * 8 + t0 + c]; }

  const int l7 = lane & 7, lq = lane >> 4, l15 = lane & 15;
  const int srow = lane >> 3;
  const int scg = l7 ^ srow;                  // pre-swizzled source granule
  const char* Abase = (const char*)abf;
  const char* Bbase = (const char*)bt;
  const size_t aSt0 = (size_t)(bm + wv * 16 + srow) * 2048 + scg * 16;
  const size_t bSt0 = (size_t)(bn + wv * 16 + srow) * 2048 + scg * 16;
  const int sDst = wv * 2048;                 // wave-uniform LDS dest
  const int aRd = (wr * 64 + l15) * 128;
  const int bRd = 32768 + (wc * 32 + l15) * 128;
  const int g0 = ((lq) ^ l7) * 16;            // ks=0 granule
  const int g1 = ((4 + lq) ^ l7) * 16;        // ks=1 granule

#define STAGE_A(bufo, h, js_) do {                                          \
    int js = (js_); if (js > 31) js = 31;                                   \
    const char* s_ = Abase + aSt0 + (size_t)(h) * 262144 + (js & 15) * 128; \
    __builtin_amdgcn_global_load_lds((const AS1 void*)s_,                   \
        (AS3 void*)(lds + (bufo) + (h) * 16384 + sDst), 16, 0, 0);          \
    __builtin_amdgcn_global_load_lds((const AS1 void*)(s_ + 16384),         \
        (AS3 void*)(lds + (bufo) + (h) * 16384 + sDst + 1024), 16, 0, 0);   \
  } while (0)
#define STAGE_B(bufo, g, js_) do {                                          \
    int js = (js_); if (js > 31) js = 31;                                   \
    const char* s_ = Bbase + (size_t)(t0 + (js >> 4)) * 2097152             \
                   + bSt0 + (size_t)(g) * 262144 + (js & 15) * 128;         \
    __builtin_amdgcn_global_load_lds((const AS1 void*)s_,                   \
        (AS3 void*)(lds + (bufo) + 32768 + (g) * 16384 + sDst), 16, 0, 0);  \
    __builtin_amdgcn_global_load_lds((const AS1 void*)(s_ + 16384),         \
        (AS3 void*)(lds + (bufo) + 32768 + (g) * 16384 + sDst + 1024), 16, 0, 0); \
  } while (0)
#define LDA(bufo, h, ar) do {                                               \
    const char* p_ = lds + (bufo) + (h) * 16384 + aRd;                      \
    _Pragma("unroll") for (int mm = 0; mm < 4; ++mm) {                      \
      ar[mm][0] = *(const bf16x8*)(p_ + mm * 2048 + g0);                    \
      ar[mm][1] = *(const bf16x8*)(p_ + mm * 2048 + g1); }                  \
  } while (0)
#define LDB(bufo, g, br) do {                                               \
    const char* p_ = lds + (bufo) + (g) * 16384 + bRd;                      \
    _Pragma("unroll") for (int nn = 0; nn < 2; ++nn) {                      \
      br[nn][0] = *(const bf16x8*)(p_ + nn * 2048 + g0);                    \
      br[nn][1] = *(const bf16x8*)(p_ + nn * 2048 + g1); }                  \
  } while (0)
#define MFQ(h, g, ar, br) do {                                              \
    _Pragma("unroll") for (int mm = 0; mm < 4; ++mm)                        \
    _Pragma("unroll") for (int nn = 0; nn < 2; ++nn) {                      \
      acc[(h)*4+mm][(g)*2+nn] = __builtin_amdgcn_mfma_f32_16x16x32_bf16(    \
          ar[mm][0], br[nn][0], acc[(h)*4+mm][(g)*2+nn], 0, 0, 0);          \
      acc[(h)*4+mm][(g)*2+nn] = __builtin_amdgcn_mfma_f32_16x16x32_bf16(    \
          ar[mm][1], br[nn][1], acc[(h)*4+mm][(g)*2+nn], 0, 0, 0); }        \
  } while (0)

  f32x4 acc[8][4] = {};
  bf16x8 a0[4][2], a1[4][2], b0[2][2], b1[2][2];

  // prologue: tile0 complete -> buf0; tile1 sans A1 -> buf1 (A1(1) staged iter0 phA)
  STAGE_A(0, 0, 0); STAGE_B(0, 0, 0); STAGE_B(0, 1, 0); STAGE_A(0, 1, 0);
  STAGE_A(65536, 0, 1); STAGE_B(65536, 0, 1); STAGE_B(65536, 1, 1);
  VM6(); BAR();

  for (int j = 0; j < 32; ++j) {
    const int bufc = (j & 1) * 65536, bufn = bufc ^ 65536;
    if (j == 16) {   // t-boundary: acc *= att_t0/att_t1 (ratio fold)
#pragma unroll
      for (int m = 0; m < 8; ++m) {
        const int h_ = m >> 2, mm_ = m & 3;
#pragma unroll
        for (int ii = 0; ii < 4; ++ii) {
          const int r_ = h_ * 128 + wr * 64 + mm_ * 16 + lq * 4 + ii;
          const float sc = lAtt[r_ * 2] / lAtt[r_ * 2 + 1];
#pragma unroll
          for (int n = 0; n < 4; ++n) acc[m][n][ii] *= sc;
        }
      }
    }
    // phA: read A0,B0,B1 of tile j; stage A1(j+1) -> buf^1
    LDA(bufc, 0, a0); LDB(bufc, 0, b0); LDB(bufc, 1, b1);
    STAGE_A(bufn, 1, j + 1);
    BAR(); LGKM0();
    __builtin_amdgcn_s_setprio(1);
    MFQ(0, 0, a0, b0); MFQ(0, 1, a0, b1);
    __builtin_amdgcn_s_setprio(0);
    VM8(); BAR();
    // phB: read A1 of tile j; stage A0,B0,B1(j+2) -> buf (b0,b1 live in regs)
    LDA(bufc, 1, a1);
    STAGE_A(bufc, 0, j + 2); STAGE_B(bufc, 0, j + 2); STAGE_B(bufc, 1, j + 2);
    BAR(); LGKM0();
    __builtin_amdgcn_s_setprio(1);
    MFQ(1, 1, a1, b1); MFQ(1, 0, a1, b0);
    __builtin_amdgcn_s_setprio(0);
    VM8(); BAR();
  }

  // epilogue: scale by att_t1, atomic-accumulate across z-splits
#pragma unroll
  for (int m = 0; m < 8; ++m) {
    const int h_ = m >> 2, mm_ = m & 3;
#pragma unroll
    for (int ii = 0; ii < 4; ++ii) {
      const int rl = h_ * 128 + wr * 64 + mm_ * 16 + lq * 4 + ii;
      const float sc = lAtt[rl * 2 + 1];
      const int row = bm + rl;
#pragma unroll
      for (int n = 0; n < 4; ++n) {
        const int g_ = n >> 1, nn_ = n & 1;
        const int col = bn + g_ * 128 + wc * 32 + nn_ * 16 + l15;
        unsafeAtomicAdd(&out[(size_t)row * 1024 + col], acc[m][n][ii] * sc);
      }
    }
  }
#undef STAGE_A
#undef STAGE_B
#undef LDA
#undef LDB
#undef MFQ
}

extern "C" void kernel_launch(void* const* d_in, const int* in_sizes, int n_in,
                              void* d_out, int out_size, void* d_ws, size_t ws_size,
                              hipStream_t stream) {
  (void)in_sizes; (void)n_in; (void)ws_size;
  const float* x      = (const float*)d_in[0];   // (512,8,1024)
  const float* w      = (const float*)d_in[1];   // (8,1024,1024)
  const float* wread  = (const float*)d_in[2];   // (1,1024,16)
  const float* wwrite = (const float*)d_in[3];   // (8,1024,16)
  float* out = (float*)d_out;                    // (512,8,1024) f32

  char* ws = (char*)d_ws;
  u16*   Abf = (u16*)ws;                                    // 8 MiB
  u16*   BT  = (u16*)(ws + (8ull << 20));                   // 16 MiB
  u16*   BT2 = (u16*)(ws + (24ull << 20));                  // 288 KiB
  float* P   = (float*)(ws + (25ull << 20));                // 2.25 MiB
  float* att = (float*)(ws + (28ull << 20));                // 128 KiB
  float* W2f = (float*)(ws + (28ull << 20) + (128ull << 10)); // 512 KiB

  k_convert_x<<<4096, 256, 0, stream>>>(x, Abf);
  k_transpose_w<<<dim3(16, 16, 8), 256, 0, stream>>>(w, BT);
  hipMemsetAsync(W2f, 0, 8 * 1024 * 16 * sizeof(float), stream);
  hipMemsetAsync(P, 0, 4096 * 144 * sizeof(float), stream);
  k_w2<<<dim3(8, 8, 4), 256, 0, stream>>>(w, wwrite, W2f);
  k_bt2<<<576, 256, 0, stream>>>(wread, W2f, BT2);
  k_p<<<dim3(64, 4), 256, 0, stream>>>(Abf, BT2, P);
  k_soft<<<128, 256, 0, stream>>>(P, att);
  hipMemsetAsync(d_out, 0, (size_t)out_size * sizeof(float), stream);
  k_gemm256<<<dim3(4, 16, 4), 512, 0, stream>>>(Abf, BT, att, out);
}

// Round 6
// 129.414 us; speedup vs baseline: 5.3855x; 1.2803x over previous
//
#include <hip/hip_runtime.h>
#include <stdint.h>

typedef unsigned short u16;
typedef __attribute__((ext_vector_type(8))) short bf16x8;
typedef __attribute__((ext_vector_type(4))) float f32x4;
typedef __attribute__((ext_vector_type(4))) unsigned short u16x4;

#define AS1 __attribute__((address_space(1)))
#define AS3 __attribute__((address_space(3)))

static __device__ __forceinline__ u16 f2bf(float f) {
  union { float f; uint32_t u; } c; c.f = f;
  return (u16)((c.u + 0x7FFFu + ((c.u >> 16) & 1u)) >> 16);
}

// ---- x (f32) -> bf16 ----
__global__ __launch_bounds__(256) void k_convert_x(const float* __restrict__ x,
                                                   u16* __restrict__ abf) {
  int i = blockIdx.x * 256 + threadIdx.x;
  float4 v = reinterpret_cast<const float4*>(x)[i];
  u16x4 o = { f2bf(v.x), f2bf(v.y), f2bf(v.z), f2bf(v.w) };
  reinterpret_cast<u16x4*>(abf)[i] = o;
}

// ---- w[t][d][e] f32 -> bt[t][e][d] bf16 ----
__global__ __launch_bounds__(256) void k_transpose_w(const float* __restrict__ w,
                                                     u16* __restrict__ bt) {
  __shared__ u16 tile[64][65];
  const int t = blockIdx.z;
  const int e0 = blockIdx.x * 64, d0 = blockIdx.y * 64;
  const int tx = threadIdx.x & 63, ty = threadIdx.x >> 6;
  const float* wp = w + ((size_t)t << 20);
  u16* bp = bt + ((size_t)t << 20);
  for (int rr = 0; rr < 16; ++rr) {
    int r = rr * 4 + ty;
    tile[r][tx] = f2bf(wp[(size_t)(d0 + r) * 1024 + (e0 + tx)]);
  }
  __syncthreads();
  for (int rr = 0; rr < 16; ++rr) {
    int r = rr * 4 + ty;
    bp[(size_t)(e0 + r) * 1024 + (d0 + tx)] = tile[tx][r];
  }
}

// ---- W2f[t][d][k] += w[t][d,:]·ww[t][:,k] over e-range; MFMA, e-split x4 ----
__global__ __launch_bounds__(256) void k_w2(const float* __restrict__ w,
                                            const float* __restrict__ ww,
                                            float* __restrict__ w2f) {
  __shared__ float wwT[16][264];
  const int tid = threadIdx.x, lane = tid & 63, wv = tid >> 6;
  const int t = blockIdx.y;
  const int d0 = blockIdx.x * 128 + wv * 32;
  const int ez = blockIdx.z * 256;
  const int fr = lane & 15, koff = (lane >> 4) * 8;
  const float* wp = w + ((size_t)t << 20);
  const float* wwp = ww + (t << 14);
  for (int it = 0; it < 16; ++it) {
    int idx = it * 256 + tid;   // 4096 = 256 e x 16 k
    wwT[idx & 15][idx >> 4] = wwp[(size_t)(ez + (idx >> 4)) * 16 + (idx & 15)];
  }
  __syncthreads();
  f32x4 acc[2] = {};
  for (int kk = 0; kk < 256; kk += 32) {
    const int eL = kk + koff;
    float4 b0 = *(const float4*)&wwT[fr][eL];
    float4 b1 = *(const float4*)&wwT[fr][eL + 4];
    bf16x8 b;
    ((u16*)&b)[0] = f2bf(b0.x); ((u16*)&b)[1] = f2bf(b0.y);
    ((u16*)&b)[2] = f2bf(b0.z); ((u16*)&b)[3] = f2bf(b0.w);
    ((u16*)&b)[4] = f2bf(b1.x); ((u16*)&b)[5] = f2bf(b1.y);
    ((u16*)&b)[6] = f2bf(b1.z); ((u16*)&b)[7] = f2bf(b1.w);
#pragma unroll
    for (int m = 0; m < 2; ++m) {
      const float* ap = wp + (size_t)(d0 + m * 16 + fr) * 1024 + ez + eL;
      float4 a0 = *(const float4*)ap;
      float4 a1 = *(const float4*)(ap + 4);
      bf16x8 a;
      ((u16*)&a)[0] = f2bf(a0.x); ((u16*)&a)[1] = f2bf(a0.y);
      ((u16*)&a)[2] = f2bf(a0.z); ((u16*)&a)[3] = f2bf(a0.w);
      ((u16*)&a)[4] = f2bf(a1.x); ((u16*)&a)[5] = f2bf(a1.y);
      ((u16*)&a)[6] = f2bf(a1.z); ((u16*)&a)[7] = f2bf(a1.w);
      acc[m] = __builtin_amdgcn_mfma_f32_16x16x32_bf16(a, b, acc[m], 0, 0, 0);
    }
  }
#pragma unroll
  for (int m = 0; m < 2; ++m)
#pragma unroll
    for (int i = 0; i < 4; ++i) {
      int d = d0 + m * 16 + ((lane >> 4) << 2) + i;
      unsafeAtomicAdd(&w2f[(((size_t)t << 10) + d) * 16 + fr], acc[m][i]);
    }
}

// ---- BT2[144][1024] bf16 = [wread | W2]^T ----
__global__ __launch_bounds__(256) void k_bt2(const float* __restrict__ wread,
                                             const float* __restrict__ w2f,
                                             u16* __restrict__ bt2) {
  int i = blockIdx.x * 256 + threadIdx.x;   // < 147456
  int r = i >> 10, d = i & 1023;
  float v;
  if (r < 16) v = wread[d * 16 + r];
  else { int t = (r - 16) >> 4, k = (r - 16) & 15; v = w2f[(((size_t)t << 10) + d) * 16 + k]; }
  bt2[i] = f2bf(v);
}

// ---- P[n][144] += Abf @ BT2^T over k-range; k-split x4 ----
__global__ __launch_bounds__(256) void k_p(const u16* __restrict__ abf,
                                           const u16* __restrict__ bt2,
                                           float* __restrict__ P) {
  const int tid = threadIdx.x, lane = tid & 63, wv = tid >> 6;
  const int row0 = blockIdx.x * 64 + wv * 16;
  const int k0 = blockIdx.y * 256;
  const int fr = lane & 15, koff = (lane >> 4) * 8;
  f32x4 acc[9] = {};
  for (int kk = 0; kk < 256; kk += 32) {
    bf16x8 a = *(const bf16x8*)&abf[(size_t)(row0 + fr) * 1024 + k0 + kk + koff];
#pragma unroll
    for (int n = 0; n < 9; ++n) {
      bf16x8 b = *(const bf16x8*)&bt2[(size_t)(n * 16 + fr) * 1024 + k0 + kk + koff];
      acc[n] = __builtin_amdgcn_mfma_f32_16x16x32_bf16(a, b, acc[n], 0, 0, 0);
    }
  }
  const int rbase = row0 + ((lane >> 4) << 2);
#pragma unroll
  for (int n = 0; n < 9; ++n)
#pragma unroll
    for (int i = 0; i < 4; ++i)
      unsafeAtomicAdd(&P[(size_t)(rbase + i) * 144 + n * 16 + fr], acc[n][i]);
}

// ---- logits -> softmax -> att[n][8] ----
__global__ __launch_bounds__(256) void k_soft(const float* __restrict__ P,
                                              float* __restrict__ att) {
  __shared__ float lg[32][8];
  const int rl = threadIdx.x >> 3, tt = threadIdx.x & 7;
  const int r = blockIdx.x * 32 + rl;
  const float* p = P + (size_t)r * 144;
  float4 x0 = *(const float4*)(p),     x1 = *(const float4*)(p + 4),
         x2 = *(const float4*)(p + 8), x3 = *(const float4*)(p + 12);
  const float* q = p + 16 + tt * 16;
  float4 y0 = *(const float4*)(q),     y1 = *(const float4*)(q + 4),
         y2 = *(const float4*)(q + 8), y3 = *(const float4*)(q + 12);
  float acc = x0.x*y0.x + x0.y*y0.y + x0.z*y0.z + x0.w*y0.w
            + x1.x*y1.x + x1.y*y1.y + x1.z*y1.z + x1.w*y1.w
            + x2.x*y2.x + x2.y*y2.y + x2.z*y2.z + x2.w*y2.w
            + x3.x*y3.x + x3.y*y3.y + x3.z*y3.z + x3.w*y3.w;
  lg[rl][tt] = acc;
  __syncthreads();
  float m = lg[rl][0];
#pragma unroll
  for (int j = 1; j < 8; ++j) m = fmaxf(m, lg[rl][j]);
  float s = 0.f;
#pragma unroll
  for (int j = 0; j < 8; ++j) s += __expf(lg[rl][j] - m);
  att[(size_t)r * 8 + tt] = __expf(lg[rl][tt] - m) / s;
}

// ======== main GEMM: round-3 loop (best measured) + templated epilogue ========
// MODE 0: atomic-add into out (fallback).  MODE 1: plain stores to f32 partial[z].
// MODE 2: plain stores to bf16 partial[z].  Partials reduced by k_reduce.
#define BAR()   asm volatile("s_barrier" ::: "memory")
#define LGKM0() asm volatile("s_waitcnt lgkmcnt(0)" ::: "memory")
#define VM6()   asm volatile("s_waitcnt vmcnt(6)" ::: "memory")
#define VM0()   asm volatile("s_waitcnt vmcnt(0)" ::: "memory")

template <int MODE>
__global__ __launch_bounds__(512, 2) void k_gemm256(const u16* __restrict__ abf,
                                                    const u16* __restrict__ bt,
                                                    const float* __restrict__ att,
                                                    float* __restrict__ out,
                                                    char* __restrict__ part) {
  __shared__ char lds[133120];
  float* lAtt = (float*)(lds + 131072);   // [256][2]

  const int tid = threadIdx.x;
  const int lane = tid & 63;
  const int wv = tid >> 6;            // 0..7
  const int wr = wv >> 2, wc = wv & 3;

  int id = (blockIdx.z * gridDim.y + blockIdx.y) * gridDim.x + blockIdx.x; // 0..255
  int sw = (id & 7) * 32 + (id >> 3);         // XCD chunk swizzle (bijective)
  const int bx = sw & 3, by = (sw >> 2) & 15, bz = sw >> 6;
  const int bm = by * 256, bn = bx * 256, t0 = bz * 2;

  { int r = tid >> 1, c = tid & 1;
    lAtt[r * 2 + c] = att[(size_t)(bm + r) * 8 + t0 + c]; }

  const int l7 = lane & 7, lq = lane >> 4, l15 = lane & 15;
  const int srow = lane >> 3;
  const int scg = l7 ^ srow;                  // pre-swizzled source granule
  const char* Abase = (const char*)abf;
  const char* Bbase = (const char*)bt;
  const size_t aSt0 = (size_t)(bm + wv * 16 + srow) * 2048 + scg * 16;
  const size_t bSt0 = (size_t)(bn + wv * 16 + srow) * 2048 + scg * 16;
  const int sDst = wv * 2048;                 // wave-uniform LDS dest
  const int aRd = (wr * 64 + l15) * 128;
  const int bRd = 32768 + (wc * 32 + l15) * 128;
  const int g0 = ((lq) ^ l7) * 16;            // ks=0 granule
  const int g1 = ((4 + lq) ^ l7) * 16;        // ks=1 granule

#define STAGE_A(bufo, h, tile) do {                                         \
    const char* s_ = Abase + aSt0 + (size_t)(h) * 262144 + ((tile) & 15) * 128; \
    __builtin_amdgcn_global_load_lds((const AS1 void*)s_,                   \
        (AS3 void*)(lds + (bufo) + (h) * 16384 + sDst), 16, 0, 0);          \
    __builtin_amdgcn_global_load_lds((const AS1 void*)(s_ + 16384),         \
        (AS3 void*)(lds + (bufo) + (h) * 16384 + sDst + 1024), 16, 0, 0);   \
  } while (0)
#define STAGE_B(bufo, g, tile) do {                                         \
    const char* s_ = Bbase + (size_t)(t0 + ((tile) >> 4)) * 2097152         \
                   + bSt0 + (size_t)(g) * 262144 + ((tile) & 15) * 128;     \
    __builtin_amdgcn_global_load_lds((const AS1 void*)s_,                   \
        (AS3 void*)(lds + (bufo) + 32768 + (g) * 16384 + sDst), 16, 0, 0);  \
    __builtin_amdgcn_global_load_lds((const AS1 void*)(s_ + 16384),         \
        (AS3 void*)(lds + (bufo) + 32768 + (g) * 16384 + sDst + 1024), 16, 0, 0); \
  } while (0)
#define LDA(bufo, h) do {                                                   \
    const char* p_ = lds + (bufo) + (h) * 16384 + aRd;                      \
    _Pragma("unroll") for (int mm = 0; mm < 4; ++mm) {                      \
      a[mm][0] = *(const bf16x8*)(p_ + mm * 2048 + g0);                     \
      a[mm][1] = *(const bf16x8*)(p_ + mm * 2048 + g1); }                   \
  } while (0)
#define LDB(bufo, g, br) do {                                               \
    const char* p_ = lds + (bufo) + (g) * 16384 + bRd;                      \
    _Pragma("unroll") for (int nn = 0; nn < 2; ++nn) {                      \
      br[nn][0] = *(const bf16x8*)(p_ + nn * 2048 + g0);                    \
      br[nn][1] = *(const bf16x8*)(p_ + nn * 2048 + g1); }                  \
  } while (0)
#define MFQ(h, g, br) do {                                                  \
    __builtin_amdgcn_s_setprio(1);                                          \
    _Pragma("unroll") for (int mm = 0; mm < 4; ++mm)                        \
    _Pragma("unroll") for (int nn = 0; nn < 2; ++nn) {                      \
      acc[(h)*4+mm][(g)*2+nn] = __builtin_amdgcn_mfma_f32_16x16x32_bf16(    \
          a[mm][0], br[nn][0], acc[(h)*4+mm][(g)*2+nn], 0, 0, 0);           \
      acc[(h)*4+mm][(g)*2+nn] = __builtin_amdgcn_mfma_f32_16x16x32_bf16(    \
          a[mm][1], br[nn][1], acc[(h)*4+mm][(g)*2+nn], 0, 0, 0); }         \
    __builtin_amdgcn_s_setprio(0);                                          \
  } while (0)

  f32x4 acc[8][4] = {};
  bf16x8 a[4][2], b0[2][2], b1[2][2];

  // prologue: tile0 -> buf0 (A0,B0,B1,A1), tile1 -> buf1 (A0,B0,B1)
  STAGE_A(0, 0, 0); STAGE_B(0, 0, 0); STAGE_B(0, 1, 0); STAGE_A(0, 1, 0);
  STAGE_A(65536, 0, 1); STAGE_B(65536, 0, 1); STAGE_B(65536, 1, 1);
  VM6(); BAR();

  for (int i = 0; i < 15; ++i) {
    if (i == 8) {   // t-boundary: acc *= att_t0/att_t1 (ratio fold)
#pragma unroll
      for (int m = 0; m < 8; ++m) {
        const int h_ = m >> 2, mm_ = m & 3;
#pragma unroll
        for (int ii = 0; ii < 4; ++ii) {
          const int r_ = h_ * 128 + wr * 64 + mm_ * 16 + lq * 4 + ii;
          const float sc = lAtt[r_ * 2] / lAtt[r_ * 2 + 1];
#pragma unroll
          for (int n = 0; n < 4; ++n) acc[m][n][ii] *= sc;
        }
      }
    }
    const int j1 = 2 * i + 1, j2 = 2 * i + 2, j3 = 2 * i + 3;
    // ph1
    LDA(0, 0); LDB(0, 0, b0); STAGE_A(65536, 1, j1);
    BAR(); LGKM0(); MFQ(0, 0, b0); BAR();
    // ph2
    LDB(0, 1, b1); STAGE_A(0, 0, j2);
    BAR(); LGKM0(); MFQ(0, 1, b1); BAR();
    // ph3
    LDA(0, 1); STAGE_B(0, 0, j2);
    BAR(); LGKM0(); MFQ(1, 1, b1); BAR();
    // ph4
    STAGE_B(0, 1, j2);
    BAR(); MFQ(1, 0, b0); VM6(); BAR();
    // ph5
    LDA(65536, 0); LDB(65536, 0, b0); STAGE_A(0, 1, j2);
    BAR(); LGKM0(); MFQ(0, 0, b0); BAR();
    // ph6
    LDB(65536, 1, b1); STAGE_A(65536, 0, j3);
    BAR(); LGKM0(); MFQ(0, 1, b1); BAR();
    // ph7
    LDA(65536, 1); STAGE_B(65536, 0, j3);
    BAR(); LGKM0(); MFQ(1, 1, b1); BAR();
    // ph8
    STAGE_B(65536, 1, j3);
    BAR(); MFQ(1, 0, b0); VM6(); BAR();
  }
  // peeled last iter (tiles 30,31): only ph1 stages (tile31.A1); drain at ph4
  LDA(0, 0); LDB(0, 0, b0); STAGE_A(65536, 1, 31);
  BAR(); LGKM0(); MFQ(0, 0, b0); BAR();
  LDB(0, 1, b1);
  BAR(); LGKM0(); MFQ(0, 1, b1); BAR();
  LDA(0, 1);
  BAR(); LGKM0(); MFQ(1, 1, b1); BAR();
  BAR(); MFQ(1, 0, b0); VM0(); BAR();
  LDA(65536, 0); LDB(65536, 0, b0);
  BAR(); LGKM0(); MFQ(0, 0, b0); BAR();
  LDB(65536, 1, b1);
  BAR(); LGKM0(); MFQ(0, 1, b1); BAR();
  LDA(65536, 1);
  BAR(); LGKM0(); MFQ(1, 1, b1); BAR();
  BAR(); MFQ(1, 0, b0); BAR();

  // epilogue: scale by att_t1; MODE 0 = atomic fan-in, MODE 1/2 = plain stores
#pragma unroll
  for (int m = 0; m < 8; ++m) {
    const int h_ = m >> 2, mm_ = m & 3;
#pragma unroll
    for (int ii = 0; ii < 4; ++ii) {
      const int rl = h_ * 128 + wr * 64 + mm_ * 16 + lq * 4 + ii;
      const float sc = lAtt[rl * 2 + 1];
      const int row = bm + rl;
#pragma unroll
      for (int n = 0; n < 4; ++n) {
        const int g_ = n >> 1, nn_ = n & 1;
        const int col = bn + g_ * 128 + wc * 32 + nn_ * 16 + l15;
        const float v = acc[m][n][ii] * sc;
        if (MODE == 0) {
          unsafeAtomicAdd(&out[(size_t)row * 1024 + col], v);
        } else if (MODE == 1) {
          ((float*)part)[((size_t)bz << 22) + (size_t)row * 1024 + col] = v;
        } else {
          ((u16*)part)[((size_t)bz << 22) + (size_t)row * 1024 + col] = f2bf(v);
        }
      }
    }
  }
#undef STAGE_A
#undef STAGE_B
#undef LDA
#undef LDB
#undef MFQ
}

// ---- sum 4 partials -> out ----
template <int MODE>
__global__ __launch_bounds__(256) void k_reduce(const char* __restrict__ part,
                                                float* __restrict__ out) {
  const size_t i = ((size_t)blockIdx.x * 256 + threadIdx.x) * 4;
  if (MODE == 1) {
    const float* p = (const float*)part;
    f32x4 s = *(const f32x4*)(p + i);
    s += *(const f32x4*)(p + (1ull << 22) + i);
    s += *(const f32x4*)(p + (2ull << 22) + i);
    s += *(const f32x4*)(p + (3ull << 22) + i);
    *(f32x4*)(out + i) = s;
  } else {
    const u16* p = (const u16*)part;
    f32x4 s = {};
#pragma unroll
    for (int z = 0; z < 4; ++z) {
      u16x4 v = *(const u16x4*)(p + ((size_t)z << 22) + i);
#pragma unroll
      for (int j = 0; j < 4; ++j) {
        union { uint32_t u; float f; } c; c.u = ((uint32_t)v[j]) << 16;
        s[j] += c.f;
      }
    }
    *(f32x4*)(out + i) = s;
  }
}

extern "C" void kernel_launch(void* const* d_in, const int* in_sizes, int n_in,
                              void* d_out, int out_size, void* d_ws, size_t ws_size,
                              hipStream_t stream) {
  (void)in_sizes; (void)n_in;
  const float* x      = (const float*)d_in[0];   // (512,8,1024)
  const float* w      = (const float*)d_in[1];   // (8,1024,1024)
  const float* wread  = (const float*)d_in[2];   // (1,1024,16)
  const float* wwrite = (const float*)d_in[3];   // (8,1024,16)
  float* out = (float*)d_out;                    // (512,8,1024) f32

  char* ws = (char*)d_ws;
  u16*   Abf = (u16*)ws;                                    // 8 MiB
  u16*   BT  = (u16*)(ws + (8ull << 20));                   // 16 MiB
  u16*   BT2 = (u16*)(ws + (24ull << 20));                  // 288 KiB
  float* P   = (float*)(ws + (25ull << 20));                // 2.25 MiB
  float* att = (float*)(ws + (28ull << 20));                // 128 KiB
  float* W2f = (float*)(ws + (28ull << 20) + (128ull << 10)); // 512 KiB
  char*  part = ws + (29ull << 20);                         // partials

  k_convert_x<<<4096, 256, 0, stream>>>(x, Abf);
  k_transpose_w<<<dim3(16, 16, 8), 256, 0, stream>>>(w, BT);
  hipMemsetAsync(W2f, 0, 8 * 1024 * 16 * sizeof(float), stream);
  hipMemsetAsync(P, 0, 4096 * 144 * sizeof(float), stream);
  k_w2<<<dim3(8, 8, 4), 256, 0, stream>>>(w, wwrite, W2f);
  k_bt2<<<576, 256, 0, stream>>>(wread, W2f, BT2);
  k_p<<<dim3(64, 4), 256, 0, stream>>>(Abf, BT2, P);
  k_soft<<<128, 256, 0, stream>>>(P, att);

  const size_t base = 29ull << 20;
  if (ws_size >= base + (4ull << 24)) {            // f32 partials (67 MiB)
    k_gemm256<1><<<dim3(4, 16, 4), 512, 0, stream>>>(Abf, BT, att, out, part);
    k_reduce<1><<<4096, 256, 0, stream>>>(part, out);
  } else if (ws_size >= base + (4ull << 23)) {     // bf16 partials (34 MiB)
    k_gemm256<2><<<dim3(4, 16, 4), 512, 0, stream>>>(Abf, BT, att, out, part);
    k_reduce<2><<<4096, 256, 0, stream>>>(part, out);
  } else {                                         // fallback: atomic fan-in
    hipMemsetAsync(d_out, 0, (size_t)out_size * sizeof(float), stream);
    k_gemm256<0><<<dim3(4, 16, 4), 512, 0, stream>>>(Abf, BT, att, out, part);
  }
}

// Round 7
// 117.105 us; speedup vs baseline: 5.9516x; 1.1051x over previous
//
#include <hip/hip_runtime.h>
#include <stdint.h>

typedef unsigned short u16;
typedef __attribute__((ext_vector_type(8))) short bf16x8;
typedef __attribute__((ext_vector_type(4))) float f32x4;
typedef __attribute__((ext_vector_type(4))) unsigned short u16x4;

#define AS1 __attribute__((address_space(1)))
#define AS3 __attribute__((address_space(3)))

static __device__ __forceinline__ u16 f2bf(float f) {
  union { float f; uint32_t u; } c; c.f = f;
  return (u16)((c.u + 0x7FFFu + ((c.u >> 16) & 1u)) >> 16);
}

// ---- x (f32) -> bf16 ----
__global__ __launch_bounds__(256) void k_convert_x(const float* __restrict__ x,
                                                   u16* __restrict__ abf) {
  int i = blockIdx.x * 256 + threadIdx.x;
  float4 v = reinterpret_cast<const float4*>(x)[i];
  u16x4 o = { f2bf(v.x), f2bf(v.y), f2bf(v.z), f2bf(v.w) };
  reinterpret_cast<u16x4*>(abf)[i] = o;
}

// ---- w[t][d][e] f32 -> bt[t][e][d] bf16 ----
__global__ __launch_bounds__(256) void k_transpose_w(const float* __restrict__ w,
                                                     u16* __restrict__ bt) {
  __shared__ u16 tile[64][65];
  const int t = blockIdx.z;
  const int e0 = blockIdx.x * 64, d0 = blockIdx.y * 64;
  const int tx = threadIdx.x & 63, ty = threadIdx.x >> 6;
  const float* wp = w + ((size_t)t << 20);
  u16* bp = bt + ((size_t)t << 20);
  for (int rr = 0; rr < 16; ++rr) {
    int r = rr * 4 + ty;
    tile[r][tx] = f2bf(wp[(size_t)(d0 + r) * 1024 + (e0 + tx)]);
  }
  __syncthreads();
  for (int rr = 0; rr < 16; ++rr) {
    int r = rr * 4 + ty;
    bp[(size_t)(e0 + r) * 1024 + (d0 + tx)] = tile[tx][r];
  }
}

// ---- W2s[z][t][d][k] = w[t][d,:]·ww[t][:,k] over e-slice z; slot stores ----
__global__ __launch_bounds__(256) void k_w2(const float* __restrict__ w,
                                            const float* __restrict__ ww,
                                            float* __restrict__ w2s) {
  __shared__ float wwT[16][264];
  const int tid = threadIdx.x, lane = tid & 63, wv = tid >> 6;
  const int t = blockIdx.y;
  const int d0 = blockIdx.x * 128 + wv * 32;
  const int ez = blockIdx.z * 256;
  const int fr = lane & 15, koff = (lane >> 4) * 8;
  const float* wp = w + ((size_t)t << 20);
  const float* wwp = ww + (t << 14);
  for (int it = 0; it < 16; ++it) {
    int idx = it * 256 + tid;   // 4096 = 256 e x 16 k
    wwT[idx & 15][idx >> 4] = wwp[(size_t)(ez + (idx >> 4)) * 16 + (idx & 15)];
  }
  __syncthreads();
  f32x4 acc[2] = {};
  for (int kk = 0; kk < 256; kk += 32) {
    const int eL = kk + koff;
    float4 b0 = *(const float4*)&wwT[fr][eL];
    float4 b1 = *(const float4*)&wwT[fr][eL + 4];
    bf16x8 b;
    ((u16*)&b)[0] = f2bf(b0.x); ((u16*)&b)[1] = f2bf(b0.y);
    ((u16*)&b)[2] = f2bf(b0.z); ((u16*)&b)[3] = f2bf(b0.w);
    ((u16*)&b)[4] = f2bf(b1.x); ((u16*)&b)[5] = f2bf(b1.y);
    ((u16*)&b)[6] = f2bf(b1.z); ((u16*)&b)[7] = f2bf(b1.w);
#pragma unroll
    for (int m = 0; m < 2; ++m) {
      const float* ap = wp + (size_t)(d0 + m * 16 + fr) * 1024 + ez + eL;
      float4 a0 = *(const float4*)ap;
      float4 a1 = *(const float4*)(ap + 4);
      bf16x8 a;
      ((u16*)&a)[0] = f2bf(a0.x); ((u16*)&a)[1] = f2bf(a0.y);
      ((u16*)&a)[2] = f2bf(a0.z); ((u16*)&a)[3] = f2bf(a0.w);
      ((u16*)&a)[4] = f2bf(a1.x); ((u16*)&a)[5] = f2bf(a1.y);
      ((u16*)&a)[6] = f2bf(a1.z); ((u16*)&a)[7] = f2bf(a1.w);
      acc[m] = __builtin_amdgcn_mfma_f32_16x16x32_bf16(a, b, acc[m], 0, 0, 0);
    }
  }
  float* slot = w2s + ((size_t)blockIdx.z << 17);   // 8*1024*16 per slot
#pragma unroll
  for (int m = 0; m < 2; ++m)
#pragma unroll
    for (int i = 0; i < 4; ++i) {
      int d = d0 + m * 16 + ((lane >> 4) << 2) + i;
      slot[(((size_t)t << 10) + d) * 16 + fr] = acc[m][i];
    }
}

// ---- BT2[144][1024] bf16 = [wread | sum_z W2s]^T ----
__global__ __launch_bounds__(256) void k_bt2(const float* __restrict__ wread,
                                             const float* __restrict__ w2s,
                                             u16* __restrict__ bt2) {
  int i = blockIdx.x * 256 + threadIdx.x;   // < 147456
  int r = i >> 10, d = i & 1023;
  float v;
  if (r < 16) v = wread[d * 16 + r];
  else {
    int t = (r - 16) >> 4, k = (r - 16) & 15;
    size_t off = (((size_t)t << 10) + d) * 16 + k;
    v = w2s[off] + w2s[(1ull << 17) + off] + w2s[(2ull << 17) + off]
      + w2s[(3ull << 17) + off];
  }
  bt2[i] = f2bf(v);
}

// ---- Ps[z][n][144] = Abf @ BT2^T over k-slice z; slot stores ----
__global__ __launch_bounds__(256) void k_p(const u16* __restrict__ abf,
                                           const u16* __restrict__ bt2,
                                           float* __restrict__ Ps) {
  const int tid = threadIdx.x, lane = tid & 63, wv = tid >> 6;
  const int row0 = blockIdx.x * 64 + wv * 16;
  const int k0 = blockIdx.y * 256;
  const int fr = lane & 15, koff = (lane >> 4) * 8;
  f32x4 acc[9] = {};
  for (int kk = 0; kk < 256; kk += 32) {
    bf16x8 a = *(const bf16x8*)&abf[(size_t)(row0 + fr) * 1024 + k0 + kk + koff];
#pragma unroll
    for (int n = 0; n < 9; ++n) {
      bf16x8 b = *(const bf16x8*)&bt2[(size_t)(n * 16 + fr) * 1024 + k0 + kk + koff];
      acc[n] = __builtin_amdgcn_mfma_f32_16x16x32_bf16(a, b, acc[n], 0, 0, 0);
    }
  }
  float* slot = Ps + (size_t)blockIdx.y * 589824;   // 4096*144 per slot
  const int rbase = row0 + ((lane >> 4) << 2);
#pragma unroll
  for (int n = 0; n < 9; ++n)
#pragma unroll
    for (int i = 0; i < 4; ++i)
      slot[(size_t)(rbase + i) * 144 + n * 16 + fr] = acc[n][i];
}

// ---- logits (sum 4 slots) -> softmax -> att[n][8] ----
__global__ __launch_bounds__(256) void k_soft(const float* __restrict__ Ps,
                                              float* __restrict__ att) {
  __shared__ float lg[32][8];
  const int rl = threadIdx.x >> 3, tt = threadIdx.x & 7;
  const int r = blockIdx.x * 32 + rl;
  const float* p = Ps + (size_t)r * 144;
  f32x4 x0 = {}, x1 = {}, x2 = {}, x3 = {};
  f32x4 y0 = {}, y1 = {}, y2 = {}, y3 = {};
#pragma unroll
  for (int z = 0; z < 4; ++z) {
    const float* pz = p + (size_t)z * 589824;
    x0 += *(const f32x4*)(pz);      x1 += *(const f32x4*)(pz + 4);
    x2 += *(const f32x4*)(pz + 8);  x3 += *(const f32x4*)(pz + 12);
    const float* qz = pz + 16 + tt * 16;
    y0 += *(const f32x4*)(qz);      y1 += *(const f32x4*)(qz + 4);
    y2 += *(const f32x4*)(qz + 8);  y3 += *(const f32x4*)(qz + 12);
  }
  float acc = x0[0]*y0[0] + x0[1]*y0[1] + x0[2]*y0[2] + x0[3]*y0[3]
            + x1[0]*y1[0] + x1[1]*y1[1] + x1[2]*y1[2] + x1[3]*y1[3]
            + x2[0]*y2[0] + x2[1]*y2[1] + x2[2]*y2[2] + x2[3]*y2[3]
            + x3[0]*y3[0] + x3[1]*y3[1] + x3[2]*y3[2] + x3[3]*y3[3];
  lg[rl][tt] = acc;
  __syncthreads();
  float m = lg[rl][0];
#pragma unroll
  for (int j = 1; j < 8; ++j) m = fmaxf(m, lg[rl][j]);
  float s = 0.f;
#pragma unroll
  for (int j = 0; j < 8; ++j) s += __expf(lg[rl][j] - m);
  att[(size_t)r * 8 + tt] = __expf(lg[rl][tt] - m) / s;
}

// ======== main GEMM: round-3 loop (frozen) + templated epilogue ========
// MODE 0: atomic-add into out (fallback).  MODE 1: f32 partial[z].
// MODE 2: bf16 partial[z].  Partials reduced by k_reduce.
#define BAR()   asm volatile("s_barrier" ::: "memory")
#define LGKM0() asm volatile("s_waitcnt lgkmcnt(0)" ::: "memory")
#define VM6()   asm volatile("s_waitcnt vmcnt(6)" ::: "memory")
#define VM0()   asm volatile("s_waitcnt vmcnt(0)" ::: "memory")

template <int MODE>
__global__ __launch_bounds__(512, 2) void k_gemm256(const u16* __restrict__ abf,
                                                    const u16* __restrict__ bt,
                                                    const float* __restrict__ att,
                                                    float* __restrict__ out,
                                                    char* __restrict__ part) {
  __shared__ char lds[133120];
  float* lAtt = (float*)(lds + 131072);   // [256][2]

  const int tid = threadIdx.x;
  const int lane = tid & 63;
  const int wv = tid >> 6;            // 0..7
  const int wr = wv >> 2, wc = wv & 3;

  int id = (blockIdx.z * gridDim.y + blockIdx.y) * gridDim.x + blockIdx.x; // 0..255
  int sw = (id & 7) * 32 + (id >> 3);         // XCD chunk swizzle (bijective)
  const int bx = sw & 3, by = (sw >> 2) & 15, bz = sw >> 6;
  const int bm = by * 256, bn = bx * 256, t0 = bz * 2;

  { int r = tid >> 1, c = tid & 1;
    lAtt[r * 2 + c] = att[(size_t)(bm + r) * 8 + t0 + c]; }

  const int l7 = lane & 7, lq = lane >> 4, l15 = lane & 15;
  const int srow = lane >> 3;
  const int scg = l7 ^ srow;                  // pre-swizzled source granule
  const char* Abase = (const char*)abf;
  const char* Bbase = (const char*)bt;
  const size_t aSt0 = (size_t)(bm + wv * 16 + srow) * 2048 + scg * 16;
  const size_t bSt0 = (size_t)(bn + wv * 16 + srow) * 2048 + scg * 16;
  const int sDst = wv * 2048;                 // wave-uniform LDS dest
  const int aRd = (wr * 64 + l15) * 128;
  const int bRd = 32768 + (wc * 32 + l15) * 128;
  const int g0 = ((lq) ^ l7) * 16;            // ks=0 granule
  const int g1 = ((4 + lq) ^ l7) * 16;        // ks=1 granule

#define STAGE_A(bufo, h, tile) do {                                         \
    const char* s_ = Abase + aSt0 + (size_t)(h) * 262144 + ((tile) & 15) * 128; \
    __builtin_amdgcn_global_load_lds((const AS1 void*)s_,                   \
        (AS3 void*)(lds + (bufo) + (h) * 16384 + sDst), 16, 0, 0);          \
    __builtin_amdgcn_global_load_lds((const AS1 void*)(s_ + 16384),         \
        (AS3 void*)(lds + (bufo) + (h) * 16384 + sDst + 1024), 16, 0, 0);   \
  } while (0)
#define STAGE_B(bufo, g, tile) do {                                         \
    const char* s_ = Bbase + (size_t)(t0 + ((tile) >> 4)) * 2097152         \
                   + bSt0 + (size_t)(g) * 262144 + ((tile) & 15) * 128;     \
    __builtin_amdgcn_global_load_lds((const AS1 void*)s_,                   \
        (AS3 void*)(lds + (bufo) + 32768 + (g) * 16384 + sDst), 16, 0, 0);  \
    __builtin_amdgcn_global_load_lds((const AS1 void*)(s_ + 16384),         \
        (AS3 void*)(lds + (bufo) + 32768 + (g) * 16384 + sDst + 1024), 16, 0, 0); \
  } while (0)
#define LDA(bufo, h) do {                                                   \
    const char* p_ = lds + (bufo) + (h) * 16384 + aRd;                      \
    _Pragma("unroll") for (int mm = 0; mm < 4; ++mm) {                      \
      a[mm][0] = *(const bf16x8*)(p_ + mm * 2048 + g0);                     \
      a[mm][1] = *(const bf16x8*)(p_ + mm * 2048 + g1); }                   \
  } while (0)
#define LDB(bufo, g, br) do {                                               \
    const char* p_ = lds + (bufo) + (g) * 16384 + bRd;                      \
    _Pragma("unroll") for (int nn = 0; nn < 2; ++nn) {                      \
      br[nn][0] = *(const bf16x8*)(p_ + nn * 2048 + g0);                    \
      br[nn][1] = *(const bf16x8*)(p_ + nn * 2048 + g1); }                  \
  } while (0)
#define MFQ(h, g, br) do {                                                  \
    __builtin_amdgcn_s_setprio(1);                                          \
    _Pragma("unroll") for (int mm = 0; mm < 4; ++mm)                        \
    _Pragma("unroll") for (int nn = 0; nn < 2; ++nn) {                      \
      acc[(h)*4+mm][(g)*2+nn] = __builtin_amdgcn_mfma_f32_16x16x32_bf16(    \
          a[mm][0], br[nn][0], acc[(h)*4+mm][(g)*2+nn], 0, 0, 0);           \
      acc[(h)*4+mm][(g)*2+nn] = __builtin_amdgcn_mfma_f32_16x16x32_bf16(    \
          a[mm][1], br[nn][1], acc[(h)*4+mm][(g)*2+nn], 0, 0, 0); }         \
    __builtin_amdgcn_s_setprio(0);                                          \
  } while (0)

  f32x4 acc[8][4] = {};
  bf16x8 a[4][2], b0[2][2], b1[2][2];

  // prologue: tile0 -> buf0 (A0,B0,B1,A1), tile1 -> buf1 (A0,B0,B1)
  STAGE_A(0, 0, 0); STAGE_B(0, 0, 0); STAGE_B(0, 1, 0); STAGE_A(0, 1, 0);
  STAGE_A(65536, 0, 1); STAGE_B(65536, 0, 1); STAGE_B(65536, 1, 1);
  VM6(); BAR();

  for (int i = 0; i < 15; ++i) {
    if (i == 8) {   // t-boundary: acc *= att_t0/att_t1 (ratio fold)
#pragma unroll
      for (int m = 0; m < 8; ++m) {
        const int h_ = m >> 2, mm_ = m & 3;
#pragma unroll
        for (int ii = 0; ii < 4; ++ii) {
          const int r_ = h_ * 128 + wr * 64 + mm_ * 16 + lq * 4 + ii;
          const float sc = lAtt[r_ * 2] / lAtt[r_ * 2 + 1];
#pragma unroll
          for (int n = 0; n < 4; ++n) acc[m][n][ii] *= sc;
        }
      }
    }
    const int j1 = 2 * i + 1, j2 = 2 * i + 2, j3 = 2 * i + 3;
    // ph1
    LDA(0, 0); LDB(0, 0, b0); STAGE_A(65536, 1, j1);
    BAR(); LGKM0(); MFQ(0, 0, b0); BAR();
    // ph2
    LDB(0, 1, b1); STAGE_A(0, 0, j2);
    BAR(); LGKM0(); MFQ(0, 1, b1); BAR();
    // ph3
    LDA(0, 1); STAGE_B(0, 0, j2);
    BAR(); LGKM0(); MFQ(1, 1, b1); BAR();
    // ph4
    STAGE_B(0, 1, j2);
    BAR(); MFQ(1, 0, b0); VM6(); BAR();
    // ph5
    LDA(65536, 0); LDB(65536, 0, b0); STAGE_A(0, 1, j2);
    BAR(); LGKM0(); MFQ(0, 0, b0); BAR();
    // ph6
    LDB(65536, 1, b1); STAGE_A(65536, 0, j3);
    BAR(); LGKM0(); MFQ(0, 1, b1); BAR();
    // ph7
    LDA(65536, 1); STAGE_B(65536, 0, j3);
    BAR(); LGKM0(); MFQ(1, 1, b1); BAR();
    // ph8
    STAGE_B(65536, 1, j3);
    BAR(); MFQ(1, 0, b0); VM6(); BAR();
  }
  // peeled last iter (tiles 30,31): only ph1 stages (tile31.A1); drain at ph4
  LDA(0, 0); LDB(0, 0, b0); STAGE_A(65536, 1, 31);
  BAR(); LGKM0(); MFQ(0, 0, b0); BAR();
  LDB(0, 1, b1);
  BAR(); LGKM0(); MFQ(0, 1, b1); BAR();
  LDA(0, 1);
  BAR(); LGKM0(); MFQ(1, 1, b1); BAR();
  BAR(); MFQ(1, 0, b0); VM0(); BAR();
  LDA(65536, 0); LDB(65536, 0, b0);
  BAR(); LGKM0(); MFQ(0, 0, b0); BAR();
  LDB(65536, 1, b1);
  BAR(); LGKM0(); MFQ(0, 1, b1); BAR();
  LDA(65536, 1);
  BAR(); LGKM0(); MFQ(1, 1, b1); BAR();
  BAR(); MFQ(1, 0, b0); BAR();

  // epilogue: scale by att_t1; MODE 0 = atomic fan-in, MODE 1/2 = plain stores
#pragma unroll
  for (int m = 0; m < 8; ++m) {
    const int h_ = m >> 2, mm_ = m & 3;
#pragma unroll
    for (int ii = 0; ii < 4; ++ii) {
      const int rl = h_ * 128 + wr * 64 + mm_ * 16 + lq * 4 + ii;
      const float sc = lAtt[rl * 2 + 1];
      const int row = bm + rl;
#pragma unroll
      for (int n = 0; n < 4; ++n) {
        const int g_ = n >> 1, nn_ = n & 1;
        const int col = bn + g_ * 128 + wc * 32 + nn_ * 16 + l15;
        const float v = acc[m][n][ii] * sc;
        if (MODE == 0) {
          unsafeAtomicAdd(&out[(size_t)row * 1024 + col], v);
        } else if (MODE == 1) {
          ((float*)part)[((size_t)bz << 22) + (size_t)row * 1024 + col] = v;
        } else {
          ((u16*)part)[((size_t)bz << 22) + (size_t)row * 1024 + col] = f2bf(v);
        }
      }
    }
  }
#undef STAGE_A
#undef STAGE_B
#undef LDA
#undef LDB
#undef MFQ
}

// ---- sum 4 partials -> out ----
template <int MODE>
__global__ __launch_bounds__(256) void k_reduce(const char* __restrict__ part,
                                                float* __restrict__ out) {
  const size_t i = ((size_t)blockIdx.x * 256 + threadIdx.x) * 4;
  if (MODE == 1) {
    const float* p = (const float*)part;
    f32x4 s = *(const f32x4*)(p + i);
    s += *(const f32x4*)(p + (1ull << 22) + i);
    s += *(const f32x4*)(p + (2ull << 22) + i);
    s += *(const f32x4*)(p + (3ull << 22) + i);
    *(f32x4*)(out + i) = s;
  } else {
    const u16* p = (const u16*)part;
    f32x4 s = {};
#pragma unroll
    for (int z = 0; z < 4; ++z) {
      u16x4 v = *(const u16x4*)(p + ((size_t)z << 22) + i);
#pragma unroll
      for (int j = 0; j < 4; ++j) {
        union { uint32_t u; float f; } c; c.u = ((uint32_t)v[j]) << 16;
        s[j] += c.f;
      }
    }
    *(f32x4*)(out + i) = s;
  }
}

extern "C" void kernel_launch(void* const* d_in, const int* in_sizes, int n_in,
                              void* d_out, int out_size, void* d_ws, size_t ws_size,
                              hipStream_t stream) {
  (void)in_sizes; (void)n_in;
  const float* x      = (const float*)d_in[0];   // (512,8,1024)
  const float* w      = (const float*)d_in[1];   // (8,1024,1024)
  const float* wread  = (const float*)d_in[2];   // (1,1024,16)
  const float* wwrite = (const float*)d_in[3];   // (8,1024,16)
  float* out = (float*)d_out;                    // (512,8,1024) f32

  char* ws = (char*)d_ws;
  u16*   Abf = (u16*)ws;                                    // 8 MiB
  u16*   BT  = (u16*)(ws + (8ull << 20));                   // 16 MiB
  u16*   BT2 = (u16*)(ws + (24ull << 20));                  // 288 KiB
  float* Ps  = (float*)(ws + (25ull << 20));                // 9 MiB   [4][4096][144]
  float* att = (float*)(ws + (34ull << 20));                // 128 KiB
  float* W2s = (float*)(ws + (34ull << 20) + (128ull << 10)); // 2 MiB  [4][8][1024][16]
  char*  part = ws + (37ull << 20);                         // partials

  k_convert_x<<<4096, 256, 0, stream>>>(x, Abf);
  k_transpose_w<<<dim3(16, 16, 8), 256, 0, stream>>>(w, BT);
  k_w2<<<dim3(8, 8, 4), 256, 0, stream>>>(w, wwrite, W2s);
  k_bt2<<<576, 256, 0, stream>>>(wread, W2s, BT2);
  k_p<<<dim3(64, 4), 256, 0, stream>>>(Abf, BT2, Ps);
  k_soft<<<128, 256, 0, stream>>>(Ps, att);

  const size_t base = 37ull << 20;
  if (ws_size >= base + (4ull << 23)) {            // bf16 partials (34 MiB)
    k_gemm256<2><<<dim3(4, 16, 4), 512, 0, stream>>>(Abf, BT, att, out, part);
    k_reduce<2><<<4096, 256, 0, stream>>>(part, out);
  } else {                                         // fallback: atomic fan-in
    hipMemsetAsync(d_out, 0, (size_t)out_size * sizeof(float), stream);
    k_gemm256<0><<<dim3(4, 16, 4), 512, 0, stream>>>(Abf, BT, att, out, part);
  }
}

// Round 8
// 110.176 us; speedup vs baseline: 6.3259x; 1.0629x over previous
//
#include <hip/hip_runtime.h>
#include <stdint.h>

typedef unsigned short u16;
typedef __attribute__((ext_vector_type(8))) short bf16x8;
typedef __attribute__((ext_vector_type(4))) float f32x4;
typedef __attribute__((ext_vector_type(4))) unsigned short u16x4;

#define AS1 __attribute__((address_space(1)))
#define AS3 __attribute__((address_space(3)))

static __device__ __forceinline__ u16 f2bf(float f) {
  union { float f; uint32_t u; } c; c.f = f;
  return (u16)((c.u + 0x7FFFu + ((c.u >> 16) & 1u)) >> 16);
}

// ==== merged prep: [0,256) k_w2 | [256,4352) convert_x | [4352,6400) transpose_w ====
__global__ __launch_bounds__(256) void k_prep(const float* __restrict__ x,
                                              u16* __restrict__ abf,
                                              const float* __restrict__ w,
                                              u16* __restrict__ bt,
                                              const float* __restrict__ ww,
                                              float* __restrict__ w2s) {
  __shared__ char smem[16896];
  const int bid = blockIdx.x;
  const int tid = threadIdx.x;

  if (bid < 256) {
    // ---- W2s[z][t][d][k] = w[t][d,:]·ww[t][:,k] over e-slice z (MFMA) ----
    float (*wwT)[264] = (float(*)[264])smem;
    const int lane = tid & 63, wv = tid >> 6;
    const int t = (bid >> 3) & 7;
    const int d0 = (bid & 7) * 128 + wv * 32;
    const int ez4 = bid >> 6;           // e-slice 0..3
    const int ez = ez4 * 256;
    const int fr = lane & 15, koff = (lane >> 4) * 8;
    const float* wp = w + ((size_t)t << 20);
    const float* wwp = ww + (t << 14);
    for (int it = 0; it < 16; ++it) {
      int idx = it * 256 + tid;   // 4096 = 256 e x 16 k
      wwT[idx & 15][idx >> 4] = wwp[(size_t)(ez + (idx >> 4)) * 16 + (idx & 15)];
    }
    __syncthreads();
    f32x4 acc[2] = {};
    for (int kk = 0; kk < 256; kk += 32) {
      const int eL = kk + koff;
      float4 b0 = *(const float4*)&wwT[fr][eL];
      float4 b1 = *(const float4*)&wwT[fr][eL + 4];
      bf16x8 b;
      ((u16*)&b)[0] = f2bf(b0.x); ((u16*)&b)[1] = f2bf(b0.y);
      ((u16*)&b)[2] = f2bf(b0.z); ((u16*)&b)[3] = f2bf(b0.w);
      ((u16*)&b)[4] = f2bf(b1.x); ((u16*)&b)[5] = f2bf(b1.y);
      ((u16*)&b)[6] = f2bf(b1.z); ((u16*)&b)[7] = f2bf(b1.w);
#pragma unroll
      for (int m = 0; m < 2; ++m) {
        const float* ap = wp + (size_t)(d0 + m * 16 + fr) * 1024 + ez + eL;
        float4 a0 = *(const float4*)ap;
        float4 a1 = *(const float4*)(ap + 4);
        bf16x8 a;
        ((u16*)&a)[0] = f2bf(a0.x); ((u16*)&a)[1] = f2bf(a0.y);
        ((u16*)&a)[2] = f2bf(a0.z); ((u16*)&a)[3] = f2bf(a0.w);
        ((u16*)&a)[4] = f2bf(a1.x); ((u16*)&a)[5] = f2bf(a1.y);
        ((u16*)&a)[6] = f2bf(a1.z); ((u16*)&a)[7] = f2bf(a1.w);
        acc[m] = __builtin_amdgcn_mfma_f32_16x16x32_bf16(a, b, acc[m], 0, 0, 0);
      }
    }
    float* slot = w2s + ((size_t)ez4 << 17);
#pragma unroll
    for (int m = 0; m < 2; ++m)
#pragma unroll
      for (int i = 0; i < 4; ++i) {
        int d = d0 + m * 16 + ((lane >> 4) << 2) + i;
        slot[(((size_t)t << 10) + d) * 16 + fr] = acc[m][i];
      }
  } else if (bid < 4352) {
    // ---- x (f32) -> bf16 ----
    int i = (bid - 256) * 256 + tid;
    float4 v = reinterpret_cast<const float4*>(x)[i];
    u16x4 o = { f2bf(v.x), f2bf(v.y), f2bf(v.z), f2bf(v.w) };
    reinterpret_cast<u16x4*>(abf)[i] = o;
  } else {
    // ---- w[t][d][e] -> bt[t][e][d] bf16 (64x64 tiles) ----
    u16 (*tile)[65] = (u16(*)[65])smem;
    const int tb = bid - 4352;
    const int t = tb >> 8, rem = tb & 255;
    const int e0 = (rem & 15) * 64, d0 = (rem >> 4) * 64;
    const int tx = tid & 63, ty = tid >> 6;
    const float* wp = w + ((size_t)t << 20);
    u16* bp = bt + ((size_t)t << 20);
    for (int rr = 0; rr < 16; ++rr) {
      int r = rr * 4 + ty;
      tile[r][tx] = f2bf(wp[(size_t)(d0 + r) * 1024 + (e0 + tx)]);
    }
    __syncthreads();
    for (int rr = 0; rr < 16; ++rr) {
      int r = rr * 4 + ty;
      bp[(size_t)(e0 + r) * 1024 + (d0 + tx)] = tile[tx][r];
    }
  }
}

// ---- BT2[144][1024] bf16 = [wread | sum_z W2s]^T ----
__global__ __launch_bounds__(256) void k_bt2(const float* __restrict__ wread,
                                             const float* __restrict__ w2s,
                                             u16* __restrict__ bt2) {
  int i = blockIdx.x * 256 + threadIdx.x;   // < 147456
  int r = i >> 10, d = i & 1023;
  float v;
  if (r < 16) v = wread[d * 16 + r];
  else {
    int t = (r - 16) >> 4, k = (r - 16) & 15;
    size_t off = (((size_t)t << 10) + d) * 16 + k;
    v = w2s[off] + w2s[(1ull << 17) + off] + w2s[(2ull << 17) + off]
      + w2s[(3ull << 17) + off];
  }
  bt2[i] = f2bf(v);
}

// ---- Ps[z][n][144] = Abf @ BT2^T over k-slice z; slot stores ----
__global__ __launch_bounds__(256) void k_p(const u16* __restrict__ abf,
                                           const u16* __restrict__ bt2,
                                           float* __restrict__ Ps) {
  const int tid = threadIdx.x, lane = tid & 63, wv = tid >> 6;
  const int row0 = blockIdx.x * 64 + wv * 16;
  const int k0 = blockIdx.y * 256;
  const int fr = lane & 15, koff = (lane >> 4) * 8;
  f32x4 acc[9] = {};
  for (int kk = 0; kk < 256; kk += 32) {
    bf16x8 a = *(const bf16x8*)&abf[(size_t)(row0 + fr) * 1024 + k0 + kk + koff];
#pragma unroll
    for (int n = 0; n < 9; ++n) {
      bf16x8 b = *(const bf16x8*)&bt2[(size_t)(n * 16 + fr) * 1024 + k0 + kk + koff];
      acc[n] = __builtin_amdgcn_mfma_f32_16x16x32_bf16(a, b, acc[n], 0, 0, 0);
    }
  }
  float* slot = Ps + (size_t)blockIdx.y * 589824;   // 4096*144 per slot
  const int rbase = row0 + ((lane >> 4) << 2);
#pragma unroll
  for (int n = 0; n < 9; ++n)
#pragma unroll
    for (int i = 0; i < 4; ++i)
      slot[(size_t)(rbase + i) * 144 + n * 16 + fr] = acc[n][i];
}

// ---- logits (sum 4 slots) -> softmax -> att[n][8] ----
__global__ __launch_bounds__(256) void k_soft(const float* __restrict__ Ps,
                                              float* __restrict__ att) {
  __shared__ float lg[32][8];
  const int rl = threadIdx.x >> 3, tt = threadIdx.x & 7;
  const int r = blockIdx.x * 32 + rl;
  const float* p = Ps + (size_t)r * 144;
  f32x4 x0 = {}, x1 = {}, x2 = {}, x3 = {};
  f32x4 y0 = {}, y1 = {}, y2 = {}, y3 = {};
#pragma unroll
  for (int z = 0; z < 4; ++z) {
    const float* pz = p + (size_t)z * 589824;
    x0 += *(const f32x4*)(pz);      x1 += *(const f32x4*)(pz + 4);
    x2 += *(const f32x4*)(pz + 8);  x3 += *(const f32x4*)(pz + 12);
    const float* qz = pz + 16 + tt * 16;
    y0 += *(const f32x4*)(qz);      y1 += *(const f32x4*)(qz + 4);
    y2 += *(const f32x4*)(qz + 8);  y3 += *(const f32x4*)(qz + 12);
  }
  float acc = x0[0]*y0[0] + x0[1]*y0[1] + x0[2]*y0[2] + x0[3]*y0[3]
            + x1[0]*y1[0] + x1[1]*y1[1] + x1[2]*y1[2] + x1[3]*y1[3]
            + x2[0]*y2[0] + x2[1]*y2[1] + x2[2]*y2[2] + x2[3]*y2[3]
            + x3[0]*y3[0] + x3[1]*y3[1] + x3[2]*y3[2] + x3[3]*y3[3];
  lg[rl][tt] = acc;
  __syncthreads();
  float m = lg[rl][0];
#pragma unroll
  for (int j = 1; j < 8; ++j) m = fmaxf(m, lg[rl][j]);
  float s = 0.f;
#pragma unroll
  for (int j = 0; j < 8; ++j) s += __expf(lg[rl][j] - m);
  att[(size_t)r * 8 + tt] = __expf(lg[rl][tt] - m) / s;
}

// ======== main GEMM: round-3 loop (frozen) + balanced XCD decode ========
// XCD chunk (32 blocks) = {bz fixed, 8 by, 4 bx} -> per-L2 working set
// 4 MB A + 4 MB B (was 8 MB A + 4 MB B with fixed-bx chunks).
#define BAR()   asm volatile("s_barrier" ::: "memory")
#define LGKM0() asm volatile("s_waitcnt lgkmcnt(0)" ::: "memory")
#define VM6()   asm volatile("s_waitcnt vmcnt(6)" ::: "memory")
#define VM0()   asm volatile("s_waitcnt vmcnt(0)" ::: "memory")

template <int MODE>
__global__ __launch_bounds__(512, 2) void k_gemm256(const u16* __restrict__ abf,
                                                    const u16* __restrict__ bt,
                                                    const float* __restrict__ att,
                                                    float* __restrict__ out,
                                                    char* __restrict__ part) {
  __shared__ char lds[133120];
  float* lAtt = (float*)(lds + 131072);   // [256][2]

  const int tid = threadIdx.x;
  const int lane = tid & 63;
  const int wv = tid >> 6;            // 0..7
  const int wr = wv >> 2, wc = wv & 3;

  int id = (blockIdx.z * gridDim.y + blockIdx.y) * gridDim.x + blockIdx.x; // 0..255
  const int xcd = id & 7, pos = id >> 3;
  const int bz = xcd >> 1;                    // chunk-fixed t-pair
  const int by = (xcd & 1) * 8 + (pos & 7);   // 8 A-panels per chunk
  const int bx = pos >> 3;                    // 4 B-panels per chunk
  const int bm = by * 256, bn = bx * 256, t0 = bz * 2;

  { int r = tid >> 1, c = tid & 1;
    lAtt[r * 2 + c] = att[(size_t)(bm + r) * 8 + t0 + c]; }

  const int l7 = lane & 7, lq = lane >> 4, l15 = lane & 15;
  const int srow = lane >> 3;
  const int scg = l7 ^ srow;                  // pre-swizzled source granule
  const char* Abase = (const char*)abf;
  const char* Bbase = (const char*)bt;
  const size_t aSt0 = (size_t)(bm + wv * 16 + srow) * 2048 + scg * 16;
  const size_t bSt0 = (size_t)(bn + wv * 16 + srow) * 2048 + scg * 16;
  const int sDst = wv * 2048;                 // wave-uniform LDS dest
  const int aRd = (wr * 64 + l15) * 128;
  const int bRd = 32768 + (wc * 32 + l15) * 128;
  const int g0 = ((lq) ^ l7) * 16;            // ks=0 granule
  const int g1 = ((4 + lq) ^ l7) * 16;        // ks=1 granule

#define STAGE_A(bufo, h, tile) do {                                         \
    const char* s_ = Abase + aSt0 + (size_t)(h) * 262144 + ((tile) & 15) * 128; \
    __builtin_amdgcn_global_load_lds((const AS1 void*)s_,                   \
        (AS3 void*)(lds + (bufo) + (h) * 16384 + sDst), 16, 0, 0);          \
    __builtin_amdgcn_global_load_lds((const AS1 void*)(s_ + 16384),         \
        (AS3 void*)(lds + (bufo) + (h) * 16384 + sDst + 1024), 16, 0, 0);   \
  } while (0)
#define STAGE_B(bufo, g, tile) do {                                         \
    const char* s_ = Bbase + (size_t)(t0 + ((tile) >> 4)) * 2097152         \
                   + bSt0 + (size_t)(g) * 262144 + ((tile) & 15) * 128;     \
    __builtin_amdgcn_global_load_lds((const AS1 void*)s_,                   \
        (AS3 void*)(lds + (bufo) + 32768 + (g) * 16384 + sDst), 16, 0, 0);  \
    __builtin_amdgcn_global_load_lds((const AS1 void*)(s_ + 16384),         \
        (AS3 void*)(lds + (bufo) + 32768 + (g) * 16384 + sDst + 1024), 16, 0, 0); \
  } while (0)
#define LDA(bufo, h) do {                                                   \
    const char* p_ = lds + (bufo) + (h) * 16384 + aRd;                      \
    _Pragma("unroll") for (int mm = 0; mm < 4; ++mm) {                      \
      a[mm][0] = *(const bf16x8*)(p_ + mm * 2048 + g0);                     \
      a[mm][1] = *(const bf16x8*)(p_ + mm * 2048 + g1); }                   \
  } while (0)
#define LDB(bufo, g, br) do {                                               \
    const char* p_ = lds + (bufo) + (g) * 16384 + bRd;                      \
    _Pragma("unroll") for (int nn = 0; nn < 2; ++nn) {                      \
      br[nn][0] = *(const bf16x8*)(p_ + nn * 2048 + g0);                    \
      br[nn][1] = *(const bf16x8*)(p_ + nn * 2048 + g1); }                  \
  } while (0)
#define MFQ(h, g, br) do {                                                  \
    __builtin_amdgcn_s_setprio(1);                                          \
    _Pragma("unroll") for (int mm = 0; mm < 4; ++mm)                        \
    _Pragma("unroll") for (int nn = 0; nn < 2; ++nn) {                      \
      acc[(h)*4+mm][(g)*2+nn] = __builtin_amdgcn_mfma_f32_16x16x32_bf16(    \
          a[mm][0], br[nn][0], acc[(h)*4+mm][(g)*2+nn], 0, 0, 0);           \
      acc[(h)*4+mm][(g)*2+nn] = __builtin_amdgcn_mfma_f32_16x16x32_bf16(    \
          a[mm][1], br[nn][1], acc[(h)*4+mm][(g)*2+nn], 0, 0, 0); }         \
    __builtin_amdgcn_s_setprio(0);                                          \
  } while (0)

  f32x4 acc[8][4] = {};
  bf16x8 a[4][2], b0[2][2], b1[2][2];

  // prologue: tile0 -> buf0 (A0,B0,B1,A1), tile1 -> buf1 (A0,B0,B1)
  STAGE_A(0, 0, 0); STAGE_B(0, 0, 0); STAGE_B(0, 1, 0); STAGE_A(0, 1, 0);
  STAGE_A(65536, 0, 1); STAGE_B(65536, 0, 1); STAGE_B(65536, 1, 1);
  VM6(); BAR();

  for (int i = 0; i < 15; ++i) {
    if (i == 8) {   // t-boundary: acc *= att_t0/att_t1 (ratio fold)
#pragma unroll
      for (int m = 0; m < 8; ++m) {
        const int h_ = m >> 2, mm_ = m & 3;
#pragma unroll
        for (int ii = 0; ii < 4; ++ii) {
          const int r_ = h_ * 128 + wr * 64 + mm_ * 16 + lq * 4 + ii;
          const float sc = lAtt[r_ * 2] / lAtt[r_ * 2 + 1];
#pragma unroll
          for (int n = 0; n < 4; ++n) acc[m][n][ii] *= sc;
        }
      }
    }
    const int j1 = 2 * i + 1, j2 = 2 * i + 2, j3 = 2 * i + 3;
    // ph1
    LDA(0, 0); LDB(0, 0, b0); STAGE_A(65536, 1, j1);
    BAR(); LGKM0(); MFQ(0, 0, b0); BAR();
    // ph2
    LDB(0, 1, b1); STAGE_A(0, 0, j2);
    BAR(); LGKM0(); MFQ(0, 1, b1); BAR();
    // ph3
    LDA(0, 1); STAGE_B(0, 0, j2);
    BAR(); LGKM0(); MFQ(1, 1, b1); BAR();
    // ph4
    STAGE_B(0, 1, j2);
    BAR(); MFQ(1, 0, b0); VM6(); BAR();
    // ph5
    LDA(65536, 0); LDB(65536, 0, b0); STAGE_A(0, 1, j2);
    BAR(); LGKM0(); MFQ(0, 0, b0); BAR();
    // ph6
    LDB(65536, 1, b1); STAGE_A(65536, 0, j3);
    BAR(); LGKM0(); MFQ(0, 1, b1); BAR();
    // ph7
    LDA(65536, 1); STAGE_B(65536, 0, j3);
    BAR(); LGKM0(); MFQ(1, 1, b1); BAR();
    // ph8
    STAGE_B(65536, 1, j3);
    BAR(); MFQ(1, 0, b0); VM6(); BAR();
  }
  // peeled last iter (tiles 30,31): only ph1 stages (tile31.A1); drain at ph4
  LDA(0, 0); LDB(0, 0, b0); STAGE_A(65536, 1, 31);
  BAR(); LGKM0(); MFQ(0, 0, b0); BAR();
  LDB(0, 1, b1);
  BAR(); LGKM0(); MFQ(0, 1, b1); BAR();
  LDA(0, 1);
  BAR(); LGKM0(); MFQ(1, 1, b1); BAR();
  BAR(); MFQ(1, 0, b0); VM0(); BAR();
  LDA(65536, 0); LDB(65536, 0, b0);
  BAR(); LGKM0(); MFQ(0, 0, b0); BAR();
  LDB(65536, 1, b1);
  BAR(); LGKM0(); MFQ(0, 1, b1); BAR();
  LDA(65536, 1);
  BAR(); LGKM0(); MFQ(1, 1, b1); BAR();
  BAR(); MFQ(1, 0, b0); BAR();

  // epilogue: scale by att_t1; MODE 0 = atomic fan-in, MODE 2 = bf16 partials
#pragma unroll
  for (int m = 0; m < 8; ++m) {
    const int h_ = m >> 2, mm_ = m & 3;
#pragma unroll
    for (int ii = 0; ii < 4; ++ii) {
      const int rl = h_ * 128 + wr * 64 + mm_ * 16 + lq * 4 + ii;
      const float sc = lAtt[rl * 2 + 1];
      const int row = bm + rl;
#pragma unroll
      for (int n = 0; n < 4; ++n) {
        const int g_ = n >> 1, nn_ = n & 1;
        const int col = bn + g_ * 128 + wc * 32 + nn_ * 16 + l15;
        const float v = acc[m][n][ii] * sc;
        if (MODE == 0) {
          unsafeAtomicAdd(&out[(size_t)row * 1024 + col], v);
        } else {
          ((u16*)part)[((size_t)bz << 22) + (size_t)row * 1024 + col] = f2bf(v);
        }
      }
    }
  }
#undef STAGE_A
#undef STAGE_B
#undef LDA
#undef LDB
#undef MFQ
}

// ---- sum 4 bf16 partials -> out ----
__global__ __launch_bounds__(256) void k_reduce(const char* __restrict__ part,
                                                float* __restrict__ out) {
  const size_t i = ((size_t)blockIdx.x * 256 + threadIdx.x) * 4;
  const u16* p = (const u16*)part;
  f32x4 s = {};
#pragma unroll
  for (int z = 0; z < 4; ++z) {
    u16x4 v = *(const u16x4*)(p + ((size_t)z << 22) + i);
#pragma unroll
    for (int j = 0; j < 4; ++j) {
      union { uint32_t u; float f; } c; c.u = ((uint32_t)v[j]) << 16;
      s[j] += c.f;
    }
  }
  *(f32x4*)(out + i) = s;
}

extern "C" void kernel_launch(void* const* d_in, const int* in_sizes, int n_in,
                              void* d_out, int out_size, void* d_ws, size_t ws_size,
                              hipStream_t stream) {
  (void)in_sizes; (void)n_in;
  const float* x      = (const float*)d_in[0];   // (512,8,1024)
  const float* w      = (const float*)d_in[1];   // (8,1024,1024)
  const float* wread  = (const float*)d_in[2];   // (1,1024,16)
  const float* wwrite = (const float*)d_in[3];   // (8,1024,16)
  float* out = (float*)d_out;                    // (512,8,1024) f32

  char* ws = (char*)d_ws;
  u16*   Abf = (u16*)ws;                                    // 8 MiB
  u16*   BT  = (u16*)(ws + (8ull << 20));                   // 16 MiB
  u16*   BT2 = (u16*)(ws + (24ull << 20));                  // 288 KiB
  float* Ps  = (float*)(ws + (25ull << 20));                // 9 MiB   [4][4096][144]
  float* att = (float*)(ws + (34ull << 20));                // 128 KiB
  float* W2s = (float*)(ws + (34ull << 20) + (128ull << 10)); // 2 MiB  [4][8][1024][16]
  char*  part = ws + (37ull << 20);                         // bf16 partials (34 MiB)

  k_prep<<<6400, 256, 0, stream>>>(x, Abf, w, BT, wwrite, W2s);
  k_bt2<<<576, 256, 0, stream>>>(wread, W2s, BT2);
  k_p<<<dim3(64, 4), 256, 0, stream>>>(Abf, BT2, Ps);
  k_soft<<<128, 256, 0, stream>>>(Ps, att);

  const size_t base = 37ull << 20;
  if (ws_size >= base + (4ull << 23)) {            // bf16 partials fit
    k_gemm256<2><<<dim3(4, 16, 4), 512, 0, stream>>>(Abf, BT, att, out, part);
    k_reduce<<<4096, 256, 0, stream>>>(part, out);
  } else {                                         // fallback: atomic fan-in
    hipMemsetAsync(d_out, 0, (size_t)out_size * sizeof(float), stream);
    k_gemm256<0><<<dim3(4, 16, 4), 512, 0, stream>>>(Abf, BT, att, out, part);
  }
}